// Round 9
// baseline (1191.636 us; speedup 1.0000x reference)
//
#include <hip/hip_runtime.h>
#include <hip/hip_bf16.h>

typedef __bf16 bf16_t;
typedef __bf16 bf16x8 __attribute__((ext_vector_type(8)));
typedef float f32x4 __attribute__((ext_vector_type(4)));

#define MODEL_DIM 1024
#define INNER 2048
#define STATE 16
#define BATCH 2
#define SEQ 1024
#define BS (BATCH * SEQ)            // 2048 rows
#define PROJ_N (2 * INNER)          // 4096
#define BCN (INNER * STATE)         // 32768
#define NCHUNK 64
#define CLEN (SEQ / NCHUNK)         // 16

// ---------------------------------------------------------------------------
// async global->LDS, 16B per lane (wave-uniform LDS base, HW adds lane*16)
// ---------------------------------------------------------------------------
__device__ __forceinline__ void load_lds_16B(const void* g, void* l) {
  __builtin_amdgcn_global_load_lds(
      (const __attribute__((address_space(1))) unsigned int*)g,
      (__attribute__((address_space(3))) unsigned int*)l,
      16, 0, 0);
}

// ---------------------------------------------------------------------------
// f32 -> bf16 cast (vectorized, grid-stride). n must be divisible by 4.
// ---------------------------------------------------------------------------
__global__ void cast_f32_bf16(const float* __restrict__ in,
                              bf16_t* __restrict__ out, long n4) {
  long idx = (long)blockIdx.x * blockDim.x + threadIdx.x;
  long stride = (long)gridDim.x * blockDim.x;
  for (long i = idx; i < n4; i += stride) {
    float4 v = ((const float4*)in)[i];
    union { bf16_t b[4]; ushort4 u; } cv;
    cv.b[0] = (bf16_t)v.x; cv.b[1] = (bf16_t)v.y;
    cv.b[2] = (bf16_t)v.z; cv.b[3] = (bf16_t)v.w;
    ((ushort4*)out)[i] = cv.u;
  }
}

// ---------------------------------------------------------------------------
// BIG GEMM, 8-phase 256^2 template (T2+T3+T4+T5).
// ROUND-9 FIX: LDS buffer stride is 16384 ELEMENTS (256x64 bf16), not 32768
// (that was the BYTE size -- rounds 7/8 aliased buf1-A onto buf0-B and sent
// buf1-B out of bounds; deterministic corruption, identical absmax).
//
// C[2048,N] = A[2048,K]*Bt[N,K]^T, bf16 out. 256x256 tile, BK=64, 8 waves
// (2Mx4N), 512 thr, 128KiB LDS (2 bufs; even tile->buf0, odd->buf1).
// Phase (BUF,MH,NH) reads A rows {MH*64+[0,64)}U{128+MH*64+[0,64)} and
// B rows {q*64+NH*32+[0,32)}. STAGE_A/STAGE_B stage EXACTLY those sets.
// Stagger (iter i: ph1-4 tile 2i buf0, ph5-8 tile 2i+1 buf1):
//   ph1: B(2i+1)s1->buf1  ph2: A(2i+1)s1->buf1  ph3: A(2i+2)s0->buf0
//   ph4: B(2i+2)s0->buf0  ph5: B(2i+2)s1->buf0  ph6: A(2i+2)s1->buf0
//   ph7: A(2i+3)s0->buf1  ph8: B(2i+3)s0->buf1
// vmcnt(8) at every phase end (last 4 stages in flight); stage(p) forced
// complete by end of p+4, first read at p+5. Prologue: 12 loads + vmcnt(4).
// Peeled last iter: vmcnt 8,8,8,4,2,0,0,0.
// Every s_barrier is followed by asm("" ::: "memory") -- raw s_barrier is
// IntrNoMem, not a compiler fence (round-3-proven pattern).
// Swizzle: round-4-proven pair (source col (l7^lrow)*8, read slot ^l7).
// ---------------------------------------------------------------------------
__global__ __launch_bounds__(512, 2)
void gemm_big8(const bf16_t* __restrict__ Ap, const bf16_t* __restrict__ Bp,
               bf16_t* __restrict__ C, int N, int K) {
  __shared__ bf16_t As[2 * 256 * 64];   // 64 KB (buffer stride 16384 elems)
  __shared__ bf16_t Bs[2 * 256 * 64];   // 64 KB
  const int tid = threadIdx.x;
  const int wid = tid >> 6, lane = tid & 63;
  const int wm = wid >> 2, wn = wid & 3;

  // XCD-grouped mapping: 1024 blocks; xcd owns 16 bcol-tiles x 8 brow-tiles
  const int bid = blockIdx.x;
  const int xcd = bid & 7, local = bid >> 3;
  const int bcol = (xcd * 16 + (local >> 3)) * 256;
  const int brow = (local & 7) * 256;

  const int lrow = lane >> 3;                 // 0..7 row within 8-row strip
  const int l7 = lane & 7;
  const int scol = (l7 ^ lrow) * 8;           // pre-swizzled source col (bf16)
  const int r15 = lane & 15, g = lane >> 4;

  const int NT = K >> 6, NI = NT >> 1;

  f32x4 acc[8][4] = {};

#define FENCE() asm volatile("" ::: "memory")

  // A set H: rows {j*128 + H*64 + [0,64)}, per wave 8 rows (wid*8+lrow)
#define STAGE_A(BUF, T, H)                                                    \
  {                                                                           \
    _Pragma("unroll") for (int j = 0; j < 2; ++j) {                           \
      const int rs = j * 128 + (H) * 64;                                      \
      load_lds_16B(Ap + (size_t)(brow + rs + wid * 8 + lrow) * K +            \
                       (size_t)(T) * 64 + scol,                               \
                   (void*)(As + (BUF) * 16384 + rs * 64 + wid * 512));        \
    }                                                                         \
  }
  // B set H: rows {q*64 + H*32 + [0,32), q=0..3}; per (j,wid): q=2j+(wid>>2),
  // 8 contiguous rows starting at (wid&3)*8 within the 32-block
#define STAGE_B(BUF, T, H)                                                    \
  {                                                                           \
    _Pragma("unroll") for (int j = 0; j < 2; ++j) {                           \
      const int rs = (2 * j + (wid >> 2)) * 64 + (H) * 32 + (wid & 3) * 8;    \
      load_lds_16B(Bp + (size_t)(bcol + rs + lrow) * K +                      \
                       (size_t)(T) * 64 + scol,                               \
                   (void*)(Bs + (BUF) * 16384 + rs * 64));                    \
    }                                                                         \
  }

#define PHASE(BUF, MH, NH, STAGE_CODE, VMN)                                   \
  {                                                                           \
    bf16x8 af[4][2], bv[2][2];                                                \
    _Pragma("unroll") for (int m = 0; m < 4; ++m) {                           \
      int arow = wm * 128 + (MH) * 64 + m * 16 + r15;                         \
      _Pragma("unroll") for (int ks = 0; ks < 2; ++ks)                        \
        af[m][ks] = *(const bf16x8*)&As[(BUF) * 16384 + arow * 64 +           \
                                        (((ks * 4 + g) ^ l7) * 8)];           \
    }                                                                         \
    _Pragma("unroll") for (int n = 0; n < 2; ++n) {                           \
      int brw = wn * 64 + (NH) * 32 + n * 16 + r15;                           \
      _Pragma("unroll") for (int ks = 0; ks < 2; ++ks)                        \
        bv[n][ks] = *(const bf16x8*)&Bs[(BUF) * 16384 + brw * 64 +            \
                                        (((ks * 4 + g) ^ l7) * 8)];           \
    }                                                                         \
    STAGE_CODE;                                                               \
    FENCE();                                                                  \
    __builtin_amdgcn_s_barrier();                                             \
    FENCE();                                                                  \
    __builtin_amdgcn_s_setprio(1);                                            \
    _Pragma("unroll") for (int ks = 0; ks < 2; ++ks)                          \
      _Pragma("unroll") for (int m = 0; m < 4; ++m)                           \
        _Pragma("unroll") for (int n = 0; n < 2; ++n)                         \
          acc[(MH) * 4 + m][(NH) * 2 + n] =                                   \
              __builtin_amdgcn_mfma_f32_16x16x32_bf16(                        \
                  af[m][ks], bv[n][ks], acc[(MH) * 4 + m][(NH) * 2 + n],      \
                  0, 0, 0);                                                   \
    __builtin_amdgcn_s_setprio(0);                                            \
    asm volatile("s_waitcnt vmcnt(" #VMN ")" ::: "memory");                   \
    __builtin_amdgcn_s_barrier();                                             \
    FENCE();                                                                  \
  }

  // prologue: full tile 0 -> buf0 (8 loads); A(1)s0, B(1)s0 -> buf1 (4 loads)
  STAGE_A(0, 0, 0); STAGE_A(0, 0, 1); STAGE_B(0, 0, 0); STAGE_B(0, 0, 1);
  STAGE_A(1, 1, 0); STAGE_B(1, 1, 0);
  asm volatile("s_waitcnt vmcnt(4)" ::: "memory");
  __builtin_amdgcn_s_barrier();
  FENCE();

  for (int i = 0; i < NI - 1; ++i) {
    const int t1 = 2 * i + 1, t2 = 2 * i + 2, t3 = 2 * i + 3;
    PHASE(0, 0, 0, STAGE_B(1, t1, 1), 8);
    PHASE(0, 0, 1, STAGE_A(1, t1, 1), 8);
    PHASE(0, 1, 0, STAGE_A(0, t2, 0), 8);
    PHASE(0, 1, 1, STAGE_B(0, t2, 0), 8);
    PHASE(1, 0, 0, STAGE_B(0, t2, 1), 8);
    PHASE(1, 0, 1, STAGE_A(0, t2, 1), 8);
    PHASE(1, 1, 0, STAGE_A(1, t3, 0), 8);
    PHASE(1, 1, 1, STAGE_B(1, t3, 0), 8);
  }
  {  // peeled last iteration: tiles NT-2 (buf0), NT-1 (buf1)
    const int tl = NT - 1;
    PHASE(0, 0, 0, STAGE_B(1, tl, 1), 8);
    PHASE(0, 0, 1, STAGE_A(1, tl, 1), 8);
    PHASE(0, 1, 0, , 8);
    PHASE(0, 1, 1, , 4);
    PHASE(1, 0, 0, , 2);
    PHASE(1, 0, 1, , 0);
    PHASE(1, 1, 0, , 0);
    PHASE(1, 1, 1, , 0);
  }
#undef PHASE
#undef STAGE_A
#undef STAGE_B
#undef FENCE

  // epilogue: C/D 16x16 layout col=lane&15, row=(lane>>4)*4+j
#pragma unroll
  for (int mf = 0; mf < 8; ++mf) {
#pragma unroll
    for (int nf = 0; nf < 4; ++nf) {
      int col = bcol + wn * 64 + nf * 16 + r15;
#pragma unroll
      for (int j = 0; j < 4; ++j) {
        int row = brow + wm * 128 + mf * 16 + g * 4 + j;
        C[(size_t)row * N + col] = (bf16_t)acc[mf][nf][j];
      }
    }
  }
}

// ---------------------------------------------------------------------------
// BT GEMM (small, round-4 proven): 128x128 tile, BK=64, 4 waves, 16x16x32.
// T2 swizzle (0 conflicts measured) + XCD-grouped grid.
// EPI: 0 = store f32, 1 = softplus(x + bias[col]) f32, 2 = store bf16
// ---------------------------------------------------------------------------
template <int EPI>
__global__ __launch_bounds__(256)
void gemm_bt(const bf16_t* __restrict__ A, const bf16_t* __restrict__ Bt,
             void* __restrict__ C, const float* __restrict__ bias,
             int nbx, int nby, int N, int K) {
  __shared__ bf16_t Ash[128 * 64];
  __shared__ bf16_t Bsh[128 * 64];
  const int tid = threadIdx.x;
  const int wave = tid >> 6, lane = tid & 63;

  const int bid = blockIdx.x;
  const int xcd = bid & 7, local = bid >> 3;
  const int bcol = (xcd * (nbx >> 3) + local / nby) * 128;
  const int brow = (local % nby) * 128;

  const int wr = wave >> 1, wc = wave & 1;

  f32x4 acc[4][4] = {};

  const int seg_base = wave * 4;
  const int lrow = lane >> 3;
  const int scol = ((lane & 7) ^ (lrow & 7)) * 8;
  const int r15 = lane & 15, g = lane >> 4, l7 = lane & 7;

  for (int k0 = 0; k0 < K; k0 += 64) {
#pragma unroll
    for (int c = 0; c < 4; ++c) {
      int seg = seg_base + c;
      int row = seg * 8 + lrow;
      const bf16_t* ga = A + (size_t)(brow + row) * K + k0 + scol;
      load_lds_16B(ga, (void*)(Ash + seg * 512));
      const bf16_t* gb = Bt + (size_t)(bcol + row) * K + k0 + scol;
      load_lds_16B(gb, (void*)(Bsh + seg * 512));
    }
    asm volatile("s_waitcnt vmcnt(0)");
    __syncthreads();

#pragma unroll
    for (int ks = 0; ks < 2; ++ks) {
      bf16x8 af[4], bfr[4];
#pragma unroll
      for (int t = 0; t < 4; ++t) {
        int arow = wr * 64 + t * 16 + r15;
        int brw  = wc * 64 + t * 16 + r15;
        int slot = ((ks * 4 + g) ^ l7) * 8;
        af[t]  = *(const bf16x8*)&Ash[arow * 64 + slot];
        bfr[t] = *(const bf16x8*)&Bsh[brw * 64 + slot];
      }
#pragma unroll
      for (int mt = 0; mt < 4; ++mt)
#pragma unroll
        for (int nt = 0; nt < 4; ++nt)
          acc[mt][nt] = __builtin_amdgcn_mfma_f32_16x16x32_bf16(
              af[mt], bfr[nt], acc[mt][nt], 0, 0, 0);
    }
    __syncthreads();
  }

#pragma unroll
  for (int mt = 0; mt < 4; ++mt) {
#pragma unroll
    for (int nt = 0; nt < 4; ++nt) {
      int col = bcol + wc * 64 + nt * 16 + r15;
#pragma unroll
      for (int j = 0; j < 4; ++j) {
        int row = brow + wr * 64 + mt * 16 + g * 4 + j;
        float v = acc[mt][nt][j];
        size_t idx = (size_t)row * N + col;
        if (EPI == 0) {
          ((float*)C)[idx] = v;
        } else if (EPI == 1) {
          float x = v + bias[col];
          ((float*)C)[idx] = (x > 20.f) ? x : log1pf(__expf(x));
        } else {
          ((bf16_t*)C)[idx] = (bf16_t)v;
        }
      }
    }
  }
}

// ---------------------------------------------------------------------------
// depthwise causal conv(K=4) + bias + SiLU -> u (bf16); also gate = sigmoid
// ---------------------------------------------------------------------------
__global__ __launch_bounds__(256)
void conv_silu(const float* __restrict__ proj, const float* __restrict__ w_conv,
               const float* __restrict__ b_conv, bf16_t* __restrict__ u_bf,
               bf16_t* __restrict__ gate_bf) {
  int idx = blockIdx.x * 256 + threadIdx.x;     // over BATCH*SEQ*INNER
  int i = idx & (INNER - 1);
  int s = (idx >> 11) & (SEQ - 1);
  int b = idx >> 21;
  const float* up = proj + (size_t)b * SEQ * PROJ_N + i;
  float w0 = w_conv[i * 4 + 0], w1 = w_conv[i * 4 + 1];
  float w2 = w_conv[i * 4 + 2], w3 = w_conv[i * 4 + 3];
  float acc = b_conv[i];
  acc += up[(size_t)s * PROJ_N] * w3;
  if (s >= 1) acc += up[(size_t)(s - 1) * PROJ_N] * w2;
  if (s >= 2) acc += up[(size_t)(s - 2) * PROJ_N] * w1;
  if (s >= 3) acc += up[(size_t)(s - 3) * PROJ_N] * w0;
  float u = acc / (1.f + __expf(-acc));  // silu
  u_bf[idx] = (bf16_t)u;
  float gp = up[(size_t)s * PROJ_N + INNER];
  gate_bf[idx] = (bf16_t)(1.f / (1.f + __expf(-gp)));
}

// ---------------------------------------------------------------------------
// chunked selective scan, pass 1
// ---------------------------------------------------------------------------
__global__ __launch_bounds__(256)
void scan_pass1(const float* __restrict__ delta, const bf16_t* __restrict__ u,
                const bf16_t* __restrict__ bmat, const float* __restrict__ a_log,
                float* __restrict__ P, float* __restrict__ E) {
  int t = blockIdx.x * 256 + threadIdx.x;
  int i = t & (INNER - 1);
  int c = (t >> 11) & (NCHUNK - 1);
  int b = t >> 17;
  float an[STATE];
#pragma unroll
  for (int n = 0; n < STATE; ++n) an[n] = -__expf(a_log[i * STATE + n]);
  float st[STATE] = {};
  float dtsum = 0.f;
  size_t base_ch = (size_t)b * SEQ * INNER + i;
  size_t base_bc = (size_t)b * SEQ * BCN + (size_t)i * STATE;
  int s0 = c * CLEN;
  for (int s = s0; s < s0 + CLEN; ++s) {
    float dt = delta[base_ch + (size_t)s * INNER];
    float uv = (float)u[base_ch + (size_t)s * INNER];
    bf16x8 b0 = *(const bf16x8*)&bmat[base_bc + (size_t)s * BCN];
    bf16x8 b1 = *(const bf16x8*)&bmat[base_bc + (size_t)s * BCN + 8];
    float du = dt * uv;
    dtsum += dt;
#pragma unroll
    for (int n = 0; n < 8; ++n)
      st[n] = __expf(dt * an[n]) * st[n] + du * (float)b0[n];
#pragma unroll
    for (int n = 0; n < 8; ++n)
      st[8 + n] = __expf(dt * an[8 + n]) * st[8 + n] + du * (float)b1[n];
  }
  size_t pe = ((size_t)(b * NCHUNK + c) * INNER + i) * STATE;
#pragma unroll
  for (int q = 0; q < 4; ++q) {
    f32x4 vp = {__expf(dtsum * an[q * 4]), __expf(dtsum * an[q * 4 + 1]),
                __expf(dtsum * an[q * 4 + 2]), __expf(dtsum * an[q * 4 + 3])};
    *(f32x4*)&P[pe + q * 4] = vp;
    f32x4 ve = {st[q * 4], st[q * 4 + 1], st[q * 4 + 2], st[q * 4 + 3]};
    *(f32x4*)&E[pe + q * 4] = ve;
  }
}

// ---------------------------------------------------------------------------
// chunked scan, middle: sequential combine over chunks per (b,i,n)
// ---------------------------------------------------------------------------
__global__ __launch_bounds__(256)
void scan_mid(const float* __restrict__ P, float* __restrict__ E) {
  int gi = blockIdx.x * 256 + threadIdx.x;
  int n = gi & (STATE - 1);
  int i = (gi >> 4) & (INNER - 1);
  int b = gi >> 15;
  float H = 0.f;
  size_t stride = (size_t)INNER * STATE;
  size_t idx = (size_t)b * NCHUNK * stride + (size_t)i * STATE + n;
  for (int c = 0; c < NCHUNK; ++c) {
    float p = P[idx];
    float e = E[idx];
    E[idx] = H;
    H = p * H + e;
    idx += stride;
  }
}

// ---------------------------------------------------------------------------
// chunked scan, pass 2
// ---------------------------------------------------------------------------
__global__ __launch_bounds__(256)
void scan_pass2(const float* __restrict__ delta, const bf16_t* __restrict__ u,
                const bf16_t* __restrict__ bmat, const bf16_t* __restrict__ cmat,
                const bf16_t* __restrict__ gate, const float* __restrict__ a_log,
                const float* __restrict__ dvec, const float* __restrict__ E,
                bf16_t* __restrict__ mixed) {
  int t = blockIdx.x * 256 + threadIdx.x;
  int i = t & (INNER - 1);
  int c = (t >> 11) & (NCHUNK - 1);
  int b = t >> 17;
  float an[STATE];
#pragma unroll
  for (int n = 0; n < STATE; ++n) an[n] = -__expf(a_log[i * STATE + n]);
  float st[STATE];
  size_t pe = ((size_t)(b * NCHUNK + c) * INNER + i) * STATE;
#pragma unroll
  for (int q = 0; q < 4; ++q) {
    f32x4 v = *(const f32x4*)&E[pe + q * 4];
    st[q * 4] = v[0]; st[q * 4 + 1] = v[1]; st[q * 4 + 2] = v[2]; st[q * 4 + 3] = v[3];
  }
  float dd = dvec[i];
  size_t base_ch = (size_t)b * SEQ * INNER + i;
  size_t base_bc = (size_t)b * SEQ * BCN + (size_t)i * STATE;
  int s0 = c * CLEN;
  for (int s = s0; s < s0 + CLEN; ++s) {
    float dt = delta[base_ch + (size_t)s * INNER];
    float uv = (float)u[base_ch + (size_t)s * INNER];
    bf16x8 b0 = *(const bf16x8*)&bmat[base_bc + (size_t)s * BCN];
    bf16x8 b1 = *(const bf16x8*)&bmat[base_bc + (size_t)s * BCN + 8];
    bf16x8 c0 = *(const bf16x8*)&cmat[base_bc + (size_t)s * BCN];
    bf16x8 c1 = *(const bf16x8*)&cmat[base_bc + (size_t)s * BCN + 8];
    float du = dt * uv;
    float y = 0.f;
#pragma unroll
    for (int n = 0; n < 8; ++n) {
      st[n] = __expf(dt * an[n]) * st[n] + du * (float)b0[n];
      y += (float)c0[n] * st[n];
    }
#pragma unroll
    for (int n = 0; n < 8; ++n) {
      st[8 + n] = __expf(dt * an[8 + n]) * st[8 + n] + du * (float)b1[n];
      y += (float)c1[n] * st[8 + n];
    }
    float g = (float)gate[base_ch + (size_t)s * INNER];
    mixed[base_ch + (size_t)s * INNER] = (bf16_t)((y + dd * uv) * g);
  }
}

// ---------------------------------------------------------------------------
extern "C" void kernel_launch(void* const* d_in, const int* in_sizes, int n_in,
                              void* d_out, int out_size, void* d_ws, size_t ws_size,
                              hipStream_t stream) {
  const float* hidden = (const float*)d_in[0];
  const float* w_in   = (const float*)d_in[1];
  const float* w_conv = (const float*)d_in[2];
  const float* b_conv = (const float*)d_in[3];
  const float* w_dt   = (const float*)d_in[4];
  const float* b_dt   = (const float*)d_in[5];
  const float* w_b    = (const float*)d_in[6];
  const float* w_c    = (const float*)d_in[7];
  const float* w_out  = (const float*)d_in[8];
  const float* a_log  = (const float*)d_in[9];
  const float* dvec   = (const float*)d_in[10];
  float* out = (float*)d_out;

  char* ws = (char*)d_ws;
  bf16_t* hidden_bf = (bf16_t*)ws; ws += (size_t)BS * MODEL_DIM * 2;       // 4MB
  bf16_t* wsmall_bf = (bf16_t*)ws; ws += (size_t)PROJ_N * MODEL_DIM * 2;   // 8MB
  float*  proj      = (float*)ws;  ws += (size_t)BS * PROJ_N * 4;          // 32MB
  bf16_t* u_bf      = (bf16_t*)ws; ws += (size_t)BS * INNER * 2;           // 8MB
  bf16_t* gate_bf   = (bf16_t*)ws; ws += (size_t)BS * INNER * 2;           // 8MB
  float*  delta     = (float*)ws;  ws += (size_t)BS * INNER * 4;           // 16MB
  bf16_t* wbig_bf   = (bf16_t*)ws; ws += (size_t)BCN * INNER * 2;          // 128MB
  bf16_t* bmat      = (bf16_t*)ws; ws += (size_t)BS * BCN * 2;             // 128MB
  bf16_t* cmat      = (bf16_t*)ws; ws += (size_t)BS * BCN * 2;             // 128MB
  bf16_t* mixed     = (bf16_t*)ws; ws += (size_t)BS * INNER * 2;           // 8MB
  float* Pbuf = (float*)wbig_bf;                                           // 16.8MB
  float* Ebuf = Pbuf + (size_t)BATCH * NCHUNK * INNER * STATE;             // 16.8MB

  // 1. cast hidden + w_in
  cast_f32_bf16<<<2048, 256, 0, stream>>>(hidden, hidden_bf, (long)BS * MODEL_DIM / 4);
  cast_f32_bf16<<<2048, 256, 0, stream>>>(w_in, wsmall_bf, (long)PROJ_N * MODEL_DIM / 4);
  // 2. proj = hidden @ w_in.T   [2048, 4096]   nbx=32, nby=16
  gemm_bt<0><<<32 * 16, 256, 0, stream>>>(
      hidden_bf, wsmall_bf, proj, nullptr, 32, 16, PROJ_N, MODEL_DIM);
  // 3. conv + silu -> u (bf16); gate = sigmoid (bf16)
  conv_silu<<<(BATCH * SEQ * INNER) / 256, 256, 0, stream>>>(proj, w_conv, b_conv, u_bf, gate_bf);
  // 4. delta = softplus(u @ w_dt.T + b_dt)   [2048, 2048] f32   nbx=16, nby=16
  cast_f32_bf16<<<2048, 256, 0, stream>>>(w_dt, wsmall_bf, (long)INNER * INNER / 4);
  gemm_bt<1><<<16 * 16, 256, 0, stream>>>(
      u_bf, wsmall_bf, delta, b_dt, 16, 16, INNER, INNER);
  // 5. bmat = u @ w_b.T   [2048, 32768] bf16  (8-phase 256^2 kernel)
  cast_f32_bf16<<<2048, 256, 0, stream>>>(w_b, wbig_bf, (long)BCN * INNER / 4);
  gemm_big8<<<1024, 512, 0, stream>>>(u_bf, wbig_bf, bmat, BCN, INNER);
  // 6. cmat = u @ w_c.T
  cast_f32_bf16<<<2048, 256, 0, stream>>>(w_c, wbig_bf, (long)BCN * INNER / 4);
  gemm_big8<<<1024, 512, 0, stream>>>(u_bf, wbig_bf, cmat, BCN, INNER);
  // 7. chunked scan (P/E alias wbig_bf which is dead now)
  scan_pass1<<<(BATCH * NCHUNK * INNER) / 256, 256, 0, stream>>>(
      delta, u_bf, bmat, a_log, Pbuf, Ebuf);
  scan_mid<<<(BATCH * INNER * STATE) / 256, 256, 0, stream>>>(Pbuf, Ebuf);
  scan_pass2<<<(BATCH * NCHUNK * INNER) / 256, 256, 0, stream>>>(
      delta, u_bf, bmat, cmat, gate_bf, a_log, dvec, Ebuf, mixed);
  // 8. out = mixed @ w_out.T   [2048, 1024] f32   nbx=8, nby=16
  cast_f32_bf16<<<2048, 256, 0, stream>>>(w_out, wsmall_bf, (long)MODEL_DIM * INNER / 4);
  gemm_bt<0><<<8 * 16, 256, 0, stream>>>(
      mixed, wsmall_bf, out, nullptr, 8, 16, MODEL_DIM, INNER);
}

// Round 10
// 1029.631 us; speedup vs baseline: 1.1573x; 1.1573x over previous
//
#include <hip/hip_runtime.h>
#include <hip/hip_bf16.h>

typedef __bf16 bf16_t;
typedef __bf16 bf16x8 __attribute__((ext_vector_type(8)));
typedef float f32x4 __attribute__((ext_vector_type(4)));

#define MODEL_DIM 1024
#define INNER 2048
#define STATE 16
#define BATCH 2
#define SEQ 1024
#define BS (BATCH * SEQ)            // 2048 rows
#define PROJ_N (2 * INNER)          // 4096
#define BCN (INNER * STATE)         // 32768
#define NCHUNK 64
#define CLEN (SEQ / NCHUNK)         // 16

// ---------------------------------------------------------------------------
// async global->LDS, 16B per lane (wave-uniform LDS base, HW adds lane*16)
// ---------------------------------------------------------------------------
__device__ __forceinline__ void load_lds_16B(const void* g, void* l) {
  __builtin_amdgcn_global_load_lds(
      (const __attribute__((address_space(1))) unsigned int*)g,
      (__attribute__((address_space(3))) unsigned int*)l,
      16, 0, 0);
}

// ---------------------------------------------------------------------------
// f32 -> bf16 cast (vectorized, grid-stride). n must be divisible by 4.
// ---------------------------------------------------------------------------
__global__ void cast_f32_bf16(const float* __restrict__ in,
                              bf16_t* __restrict__ out, long n4) {
  long idx = (long)blockIdx.x * blockDim.x + threadIdx.x;
  long stride = (long)gridDim.x * blockDim.x;
  for (long i = idx; i < n4; i += stride) {
    float4 v = ((const float4*)in)[i];
    union { bf16_t b[4]; ushort4 u; } cv;
    cv.b[0] = (bf16_t)v.x; cv.b[1] = (bf16_t)v.y;
    cv.b[2] = (bf16_t)v.z; cv.b[3] = (bf16_t)v.w;
    ((ushort4*)out)[i] = cv.u;
  }
}

// ---------------------------------------------------------------------------
// BIG GEMM, 8-phase 256^2, ROUND-10: register-fragment reuse across phases.
// Round 9 (passing) re-read all 12 b128 frags EVERY phase -> LDS-read-bound
// (MfmaUtil 29%). Now per tile: ph1 reads A(MH0)+B0 (12), ph2 reads B1 (4),
// ph3 reads A(MH1) (8, reuses B0), ph4 reads NOTHING (reuses A,B1):
// 24 reads/tile/wave instead of 48. First-read phase of every LDS region is
// UNCHANGED (A.s0@ph1, B.s0@ph1, B.s1@ph2, A.s1@ph3), so the round-9-verified
// staging stagger + vmcnt schedule is kept verbatim:
//   ph1: B(2i+1)s1->buf1  ph2: A(2i+1)s1->buf1  ph3: A(2i+2)s0->buf0
//   ph4: B(2i+2)s0->buf0  ph5: B(2i+2)s1->buf0  ph6: A(2i+2)s1->buf0
//   ph7: A(2i+3)s0->buf1  ph8: B(2i+3)s0->buf1
// vmcnt(8) every phase end; prologue 12 loads + vmcnt(4); peel ladder
// 8,8,8,4,2,0,0,0. LDS buffer stride 16384 ELEMENTS. Every s_barrier is
// wrapped in asm("" ::: "memory") fences (s_barrier is IntrNoMem).
// Swizzle: round-4-proven pair (source col (l7^lrow)*8, read slot ^l7).
// ---------------------------------------------------------------------------
__global__ __launch_bounds__(512, 2)
void gemm_big8(const bf16_t* __restrict__ Ap, const bf16_t* __restrict__ Bp,
               bf16_t* __restrict__ C, int N, int K) {
  __shared__ bf16_t As[2 * 256 * 64];   // 64 KB (buffer stride 16384 elems)
  __shared__ bf16_t Bs[2 * 256 * 64];   // 64 KB
  const int tid = threadIdx.x;
  const int wid = tid >> 6, lane = tid & 63;
  const int wm = wid >> 2, wn = wid & 3;

  // XCD-grouped mapping: 1024 blocks; xcd owns 16 bcol-tiles x 8 brow-tiles
  const int bid = blockIdx.x;
  const int xcd = bid & 7, local = bid >> 3;
  const int bcol = (xcd * 16 + (local >> 3)) * 256;
  const int brow = (local & 7) * 256;

  const int lrow = lane >> 3;                 // 0..7 row within 8-row strip
  const int l7 = lane & 7;
  const int scol = (l7 ^ lrow) * 8;           // pre-swizzled source col (bf16)
  const int r15 = lane & 15, g = lane >> 4;

  const int NT = K >> 6, NI = NT >> 1;

  f32x4 acc[8][4] = {};
  bf16x8 af[4][2], vb0[2][2], vb1[2][2];      // persistent fragments

#define FENCE() asm volatile("" ::: "memory")

  // A set H: rows {j*128 + H*64 + [0,64)}, per wave 8 rows (wid*8+lrow)
#define STAGE_A(BUF, T, H)                                                    \
  {                                                                           \
    _Pragma("unroll") for (int j = 0; j < 2; ++j) {                           \
      const int rs = j * 128 + (H) * 64;                                      \
      load_lds_16B(Ap + (size_t)(brow + rs + wid * 8 + lrow) * K +            \
                       (size_t)(T) * 64 + scol,                               \
                   (void*)(As + (BUF) * 16384 + rs * 64 + wid * 512));        \
    }                                                                         \
  }
  // B set H: rows {q*64 + H*32 + [0,32), q=0..3}; per (j,wid): q=2j+(wid>>2),
  // 8 contiguous rows starting at (wid&3)*8 within the 32-block
#define STAGE_B(BUF, T, H)                                                    \
  {                                                                           \
    _Pragma("unroll") for (int j = 0; j < 2; ++j) {                           \
      const int rs = (2 * j + (wid >> 2)) * 64 + (H) * 32 + (wid & 3) * 8;    \
      load_lds_16B(Bp + (size_t)(bcol + rs + lrow) * K +                      \
                       (size_t)(T) * 64 + scol,                               \
                   (void*)(Bs + (BUF) * 16384 + rs * 64));                    \
    }                                                                         \
  }

#define LOAD_A(BUF, MH)                                                       \
  _Pragma("unroll") for (int m = 0; m < 4; ++m) {                             \
    int arow = wm * 128 + (MH) * 64 + m * 16 + r15;                           \
    _Pragma("unroll") for (int ks = 0; ks < 2; ++ks)                          \
      af[m][ks] = *(const bf16x8*)&As[(BUF) * 16384 + arow * 64 +             \
                                      (((ks * 4 + g) ^ l7) * 8)];             \
  }
#define LOAD_B(BUF, NH, DST)                                                  \
  _Pragma("unroll") for (int n = 0; n < 2; ++n) {                             \
    int brw = wn * 64 + (NH) * 32 + n * 16 + r15;                             \
    _Pragma("unroll") for (int ks = 0; ks < 2; ++ks)                          \
      DST[n][ks] = *(const bf16x8*)&Bs[(BUF) * 16384 + brw * 64 +             \
                                       (((ks * 4 + g) ^ l7) * 8)];            \
  }

#define PHASE(MH, NH, BSEL, LOADS, STAGE_CODE, VMN)                           \
  {                                                                           \
    LOADS;                                                                    \
    STAGE_CODE;                                                               \
    FENCE();                                                                  \
    __builtin_amdgcn_s_barrier();                                             \
    FENCE();                                                                  \
    __builtin_amdgcn_s_setprio(1);                                            \
    _Pragma("unroll") for (int ks = 0; ks < 2; ++ks)                          \
      _Pragma("unroll") for (int m = 0; m < 4; ++m)                           \
        _Pragma("unroll") for (int n = 0; n < 2; ++n)                         \
          acc[(MH) * 4 + m][(NH) * 2 + n] =                                   \
              __builtin_amdgcn_mfma_f32_16x16x32_bf16(                        \
                  af[m][ks], BSEL[n][ks], acc[(MH) * 4 + m][(NH) * 2 + n],    \
                  0, 0, 0);                                                   \
    __builtin_amdgcn_s_setprio(0);                                            \
    asm volatile("s_waitcnt vmcnt(" #VMN ")" ::: "memory");                   \
    __builtin_amdgcn_s_barrier();                                             \
    FENCE();                                                                  \
  }

  // prologue: full tile 0 -> buf0 (8 loads); A(1)s0, B(1)s0 -> buf1 (4 loads)
  STAGE_A(0, 0, 0); STAGE_A(0, 0, 1); STAGE_B(0, 0, 0); STAGE_B(0, 0, 1);
  STAGE_A(1, 1, 0); STAGE_B(1, 1, 0);
  asm volatile("s_waitcnt vmcnt(4)" ::: "memory");
  __builtin_amdgcn_s_barrier();
  FENCE();

  for (int i = 0; i < NI - 1; ++i) {
    const int t1 = 2 * i + 1, t2 = 2 * i + 2, t3 = 2 * i + 3;
    PHASE(0, 0, vb0, {LOAD_A(0, 0); LOAD_B(0, 0, vb0);}, STAGE_B(1, t1, 1), 8);
    PHASE(0, 1, vb1, LOAD_B(0, 1, vb1),                  STAGE_A(1, t1, 1), 8);
    PHASE(1, 0, vb0, LOAD_A(0, 1),                       STAGE_A(0, t2, 0), 8);
    PHASE(1, 1, vb1, ,                                   STAGE_B(0, t2, 0), 8);
    PHASE(0, 0, vb0, {LOAD_A(1, 0); LOAD_B(1, 0, vb0);}, STAGE_B(0, t2, 1), 8);
    PHASE(0, 1, vb1, LOAD_B(1, 1, vb1),                  STAGE_A(0, t2, 1), 8);
    PHASE(1, 0, vb0, LOAD_A(1, 1),                       STAGE_A(1, t3, 0), 8);
    PHASE(1, 1, vb1, ,                                   STAGE_B(1, t3, 0), 8);
  }
  {  // peeled last iteration: tiles NT-2 (buf0), NT-1 (buf1)
    const int tl = NT - 1;
    PHASE(0, 0, vb0, {LOAD_A(0, 0); LOAD_B(0, 0, vb0);}, STAGE_B(1, tl, 1), 8);
    PHASE(0, 1, vb1, LOAD_B(0, 1, vb1),                  STAGE_A(1, tl, 1), 8);
    PHASE(1, 0, vb0, LOAD_A(0, 1),                       , 8);
    PHASE(1, 1, vb1, ,                                   , 4);
    PHASE(0, 0, vb0, {LOAD_A(1, 0); LOAD_B(1, 0, vb0);}, , 2);
    PHASE(0, 1, vb1, LOAD_B(1, 1, vb1),                  , 0);
    PHASE(1, 0, vb0, LOAD_A(1, 1),                       , 0);
    PHASE(1, 1, vb1, ,                                   , 0);
  }
#undef PHASE
#undef LOAD_A
#undef LOAD_B
#undef STAGE_A
#undef STAGE_B
#undef FENCE

  // epilogue: C/D 16x16 layout col=lane&15, row=(lane>>4)*4+j
#pragma unroll
  for (int mf = 0; mf < 8; ++mf) {
#pragma unroll
    for (int nf = 0; nf < 4; ++nf) {
      int col = bcol + wn * 64 + nf * 16 + r15;
#pragma unroll
      for (int j = 0; j < 4; ++j) {
        int row = brow + wm * 128 + mf * 16 + g * 4 + j;
        C[(size_t)row * N + col] = (bf16_t)acc[mf][nf][j];
      }
    }
  }
}

// ---------------------------------------------------------------------------
// BT GEMM (small, round-4 proven): 128x128 tile, BK=64, 4 waves, 16x16x32.
// T2 swizzle (0 conflicts measured) + XCD-grouped grid.
// EPI: 0 = store f32, 1 = softplus(x + bias[col]) f32, 2 = store bf16
// ---------------------------------------------------------------------------
template <int EPI>
__global__ __launch_bounds__(256)
void gemm_bt(const bf16_t* __restrict__ A, const bf16_t* __restrict__ Bt,
             void* __restrict__ C, const float* __restrict__ bias,
             int nbx, int nby, int N, int K) {
  __shared__ bf16_t Ash[128 * 64];
  __shared__ bf16_t Bsh[128 * 64];
  const int tid = threadIdx.x;
  const int wave = tid >> 6, lane = tid & 63;

  const int bid = blockIdx.x;
  const int xcd = bid & 7, local = bid >> 3;
  const int bcol = (xcd * (nbx >> 3) + local / nby) * 128;
  const int brow = (local % nby) * 128;

  const int wr = wave >> 1, wc = wave & 1;

  f32x4 acc[4][4] = {};

  const int seg_base = wave * 4;
  const int lrow = lane >> 3;
  const int scol = ((lane & 7) ^ (lrow & 7)) * 8;
  const int r15 = lane & 15, g = lane >> 4, l7 = lane & 7;

  for (int k0 = 0; k0 < K; k0 += 64) {
#pragma unroll
    for (int c = 0; c < 4; ++c) {
      int seg = seg_base + c;
      int row = seg * 8 + lrow;
      const bf16_t* ga = A + (size_t)(brow + row) * K + k0 + scol;
      load_lds_16B(ga, (void*)(Ash + seg * 512));
      const bf16_t* gb = Bt + (size_t)(bcol + row) * K + k0 + scol;
      load_lds_16B(gb, (void*)(Bsh + seg * 512));
    }
    asm volatile("s_waitcnt vmcnt(0)");
    __syncthreads();

#pragma unroll
    for (int ks = 0; ks < 2; ++ks) {
      bf16x8 af[4], bfr[4];
#pragma unroll
      for (int t = 0; t < 4; ++t) {
        int arow = wr * 64 + t * 16 + r15;
        int brw  = wc * 64 + t * 16 + r15;
        int slot = ((ks * 4 + g) ^ l7) * 8;
        af[t]  = *(const bf16x8*)&Ash[arow * 64 + slot];
        bfr[t] = *(const bf16x8*)&Bsh[brw * 64 + slot];
      }
#pragma unroll
      for (int mt = 0; mt < 4; ++mt)
#pragma unroll
        for (int nt = 0; nt < 4; ++nt)
          acc[mt][nt] = __builtin_amdgcn_mfma_f32_16x16x32_bf16(
              af[mt], bfr[nt], acc[mt][nt], 0, 0, 0);
    }
    __syncthreads();
  }

#pragma unroll
  for (int mt = 0; mt < 4; ++mt) {
#pragma unroll
    for (int nt = 0; nt < 4; ++nt) {
      int col = bcol + wc * 64 + nt * 16 + r15;
#pragma unroll
      for (int j = 0; j < 4; ++j) {
        int row = brow + wr * 64 + mt * 16 + g * 4 + j;
        float v = acc[mt][nt][j];
        size_t idx = (size_t)row * N + col;
        if (EPI == 0) {
          ((float*)C)[idx] = v;
        } else if (EPI == 1) {
          float x = v + bias[col];
          ((float*)C)[idx] = (x > 20.f) ? x : log1pf(__expf(x));
        } else {
          ((bf16_t*)C)[idx] = (bf16_t)v;
        }
      }
    }
  }
}

// ---------------------------------------------------------------------------
// depthwise causal conv(K=4) + bias + SiLU -> u (bf16); also gate = sigmoid
// ---------------------------------------------------------------------------
__global__ __launch_bounds__(256)
void conv_silu(const float* __restrict__ proj, const float* __restrict__ w_conv,
               const float* __restrict__ b_conv, bf16_t* __restrict__ u_bf,
               bf16_t* __restrict__ gate_bf) {
  int idx = blockIdx.x * 256 + threadIdx.x;     // over BATCH*SEQ*INNER
  int i = idx & (INNER - 1);
  int s = (idx >> 11) & (SEQ - 1);
  int b = idx >> 21;
  const float* up = proj + (size_t)b * SEQ * PROJ_N + i;
  float w0 = w_conv[i * 4 + 0], w1 = w_conv[i * 4 + 1];
  float w2 = w_conv[i * 4 + 2], w3 = w_conv[i * 4 + 3];
  float acc = b_conv[i];
  acc += up[(size_t)s * PROJ_N] * w3;
  if (s >= 1) acc += up[(size_t)(s - 1) * PROJ_N] * w2;
  if (s >= 2) acc += up[(size_t)(s - 2) * PROJ_N] * w1;
  if (s >= 3) acc += up[(size_t)(s - 3) * PROJ_N] * w0;
  float u = acc / (1.f + __expf(-acc));  // silu
  u_bf[idx] = (bf16_t)u;
  float gp = up[(size_t)s * PROJ_N + INNER];
  gate_bf[idx] = (bf16_t)(1.f / (1.f + __expf(-gp)));
}

// ---------------------------------------------------------------------------
// chunked selective scan, pass 1
// ---------------------------------------------------------------------------
__global__ __launch_bounds__(256)
void scan_pass1(const float* __restrict__ delta, const bf16_t* __restrict__ u,
                const bf16_t* __restrict__ bmat, const float* __restrict__ a_log,
                float* __restrict__ P, float* __restrict__ E) {
  int t = blockIdx.x * 256 + threadIdx.x;
  int i = t & (INNER - 1);
  int c = (t >> 11) & (NCHUNK - 1);
  int b = t >> 17;
  float an[STATE];
#pragma unroll
  for (int n = 0; n < STATE; ++n) an[n] = -__expf(a_log[i * STATE + n]);
  float st[STATE] = {};
  float dtsum = 0.f;
  size_t base_ch = (size_t)b * SEQ * INNER + i;
  size_t base_bc = (size_t)b * SEQ * BCN + (size_t)i * STATE;
  int s0 = c * CLEN;
  for (int s = s0; s < s0 + CLEN; ++s) {
    float dt = delta[base_ch + (size_t)s * INNER];
    float uv = (float)u[base_ch + (size_t)s * INNER];
    bf16x8 b0 = *(const bf16x8*)&bmat[base_bc + (size_t)s * BCN];
    bf16x8 b1 = *(const bf16x8*)&bmat[base_bc + (size_t)s * BCN + 8];
    float du = dt * uv;
    dtsum += dt;
#pragma unroll
    for (int n = 0; n < 8; ++n)
      st[n] = __expf(dt * an[n]) * st[n] + du * (float)b0[n];
#pragma unroll
    for (int n = 0; n < 8; ++n)
      st[8 + n] = __expf(dt * an[8 + n]) * st[8 + n] + du * (float)b1[n];
  }
  size_t pe = ((size_t)(b * NCHUNK + c) * INNER + i) * STATE;
#pragma unroll
  for (int q = 0; q < 4; ++q) {
    f32x4 vp = {__expf(dtsum * an[q * 4]), __expf(dtsum * an[q * 4 + 1]),
                __expf(dtsum * an[q * 4 + 2]), __expf(dtsum * an[q * 4 + 3])};
    *(f32x4*)&P[pe + q * 4] = vp;
    f32x4 ve = {st[q * 4], st[q * 4 + 1], st[q * 4 + 2], st[q * 4 + 3]};
    *(f32x4*)&E[pe + q * 4] = ve;
  }
}

// ---------------------------------------------------------------------------
// chunked scan, middle: sequential combine over chunks per (b,i,n)
// ---------------------------------------------------------------------------
__global__ __launch_bounds__(256)
void scan_mid(const float* __restrict__ P, float* __restrict__ E) {
  int gi = blockIdx.x * 256 + threadIdx.x;
  int n = gi & (STATE - 1);
  int i = (gi >> 4) & (INNER - 1);
  int b = gi >> 15;
  float H = 0.f;
  size_t stride = (size_t)INNER * STATE;
  size_t idx = (size_t)b * NCHUNK * stride + (size_t)i * STATE + n;
  for (int c = 0; c < NCHUNK; ++c) {
    float p = P[idx];
    float e = E[idx];
    E[idx] = H;
    H = p * H + e;
    idx += stride;
  }
}

// ---------------------------------------------------------------------------
// chunked scan, pass 2
// ---------------------------------------------------------------------------
__global__ __launch_bounds__(256)
void scan_pass2(const float* __restrict__ delta, const bf16_t* __restrict__ u,
                const bf16_t* __restrict__ bmat, const bf16_t* __restrict__ cmat,
                const bf16_t* __restrict__ gate, const float* __restrict__ a_log,
                const float* __restrict__ dvec, const float* __restrict__ E,
                bf16_t* __restrict__ mixed) {
  int t = blockIdx.x * 256 + threadIdx.x;
  int i = t & (INNER - 1);
  int c = (t >> 11) & (NCHUNK - 1);
  int b = t >> 17;
  float an[STATE];
#pragma unroll
  for (int n = 0; n < STATE; ++n) an[n] = -__expf(a_log[i * STATE + n]);
  float st[STATE];
  size_t pe = ((size_t)(b * NCHUNK + c) * INNER + i) * STATE;
#pragma unroll
  for (int q = 0; q < 4; ++q) {
    f32x4 v = *(const f32x4*)&E[pe + q * 4];
    st[q * 4] = v[0]; st[q * 4 + 1] = v[1]; st[q * 4 + 2] = v[2]; st[q * 4 + 3] = v[3];
  }
  float dd = dvec[i];
  size_t base_ch = (size_t)b * SEQ * INNER + i;
  size_t base_bc = (size_t)b * SEQ * BCN + (size_t)i * STATE;
  int s0 = c * CLEN;
  for (int s = s0; s < s0 + CLEN; ++s) {
    float dt = delta[base_ch + (size_t)s * INNER];
    float uv = (float)u[base_ch + (size_t)s * INNER];
    bf16x8 b0 = *(const bf16x8*)&bmat[base_bc + (size_t)s * BCN];
    bf16x8 b1 = *(const bf16x8*)&bmat[base_bc + (size_t)s * BCN + 8];
    bf16x8 c0 = *(const bf16x8*)&cmat[base_bc + (size_t)s * BCN];
    bf16x8 c1 = *(const bf16x8*)&cmat[base_bc + (size_t)s * BCN + 8];
    float du = dt * uv;
    float y = 0.f;
#pragma unroll
    for (int n = 0; n < 8; ++n) {
      st[n] = __expf(dt * an[n]) * st[n] + du * (float)b0[n];
      y += (float)c0[n] * st[n];
    }
#pragma unroll
    for (int n = 0; n < 8; ++n) {
      st[8 + n] = __expf(dt * an[8 + n]) * st[8 + n] + du * (float)b1[n];
      y += (float)c1[n] * st[8 + n];
    }
    float g = (float)gate[base_ch + (size_t)s * INNER];
    mixed[base_ch + (size_t)s * INNER] = (bf16_t)((y + dd * uv) * g);
  }
}

// ---------------------------------------------------------------------------
extern "C" void kernel_launch(void* const* d_in, const int* in_sizes, int n_in,
                              void* d_out, int out_size, void* d_ws, size_t ws_size,
                              hipStream_t stream) {
  const float* hidden = (const float*)d_in[0];
  const float* w_in   = (const float*)d_in[1];
  const float* w_conv = (const float*)d_in[2];
  const float* b_conv = (const float*)d_in[3];
  const float* w_dt   = (const float*)d_in[4];
  const float* b_dt   = (const float*)d_in[5];
  const float* w_b    = (const float*)d_in[6];
  const float* w_c    = (const float*)d_in[7];
  const float* w_out  = (const float*)d_in[8];
  const float* a_log  = (const float*)d_in[9];
  const float* dvec   = (const float*)d_in[10];
  float* out = (float*)d_out;

  char* ws = (char*)d_ws;
  bf16_t* hidden_bf = (bf16_t*)ws; ws += (size_t)BS * MODEL_DIM * 2;       // 4MB
  bf16_t* wsmall_bf = (bf16_t*)ws; ws += (size_t)PROJ_N * MODEL_DIM * 2;   // 8MB
  float*  proj      = (float*)ws;  ws += (size_t)BS * PROJ_N * 4;          // 32MB
  bf16_t* u_bf      = (bf16_t*)ws; ws += (size_t)BS * INNER * 2;           // 8MB
  bf16_t* gate_bf   = (bf16_t*)ws; ws += (size_t)BS * INNER * 2;           // 8MB
  float*  delta     = (float*)ws;  ws += (size_t)BS * INNER * 4;           // 16MB
  bf16_t* wbig_bf   = (bf16_t*)ws; ws += (size_t)BCN * INNER * 2;          // 128MB
  bf16_t* bmat      = (bf16_t*)ws; ws += (size_t)BS * BCN * 2;             // 128MB
  bf16_t* cmat      = (bf16_t*)ws; ws += (size_t)BS * BCN * 2;             // 128MB
  bf16_t* mixed     = (bf16_t*)ws; ws += (size_t)BS * INNER * 2;           // 8MB
  float* Pbuf = (float*)wbig_bf;                                           // 16.8MB
  float* Ebuf = Pbuf + (size_t)BATCH * NCHUNK * INNER * STATE;             // 16.8MB

  // 1. cast hidden + w_in
  cast_f32_bf16<<<2048, 256, 0, stream>>>(hidden, hidden_bf, (long)BS * MODEL_DIM / 4);
  cast_f32_bf16<<<2048, 256, 0, stream>>>(w_in, wsmall_bf, (long)PROJ_N * MODEL_DIM / 4);
  // 2. proj = hidden @ w_in.T   [2048, 4096]   nbx=32, nby=16
  gemm_bt<0><<<32 * 16, 256, 0, stream>>>(
      hidden_bf, wsmall_bf, proj, nullptr, 32, 16, PROJ_N, MODEL_DIM);
  // 3. conv + silu -> u (bf16); gate = sigmoid (bf16)
  conv_silu<<<(BATCH * SEQ * INNER) / 256, 256, 0, stream>>>(proj, w_conv, b_conv, u_bf, gate_bf);
  // 4. delta = softplus(u @ w_dt.T + b_dt)   [2048, 2048] f32   nbx=16, nby=16
  cast_f32_bf16<<<2048, 256, 0, stream>>>(w_dt, wsmall_bf, (long)INNER * INNER / 4);
  gemm_bt<1><<<16 * 16, 256, 0, stream>>>(
      u_bf, wsmall_bf, delta, b_dt, 16, 16, INNER, INNER);
  // 5. bmat = u @ w_b.T   [2048, 32768] bf16  (8-phase 256^2 kernel)
  cast_f32_bf16<<<2048, 256, 0, stream>>>(w_b, wbig_bf, (long)BCN * INNER / 4);
  gemm_big8<<<1024, 512, 0, stream>>>(u_bf, wbig_bf, bmat, BCN, INNER);
  // 6. cmat = u @ w_c.T
  cast_f32_bf16<<<2048, 256, 0, stream>>>(w_c, wbig_bf, (long)BCN * INNER / 4);
  gemm_big8<<<1024, 512, 0, stream>>>(u_bf, wbig_bf, cmat, BCN, INNER);
  // 7. chunked scan (P/E alias wbig_bf which is dead now)
  scan_pass1<<<(BATCH * NCHUNK * INNER) / 256, 256, 0, stream>>>(
      delta, u_bf, bmat, a_log, Pbuf, Ebuf);
  scan_mid<<<(BATCH * INNER * STATE) / 256, 256, 0, stream>>>(Pbuf, Ebuf);
  scan_pass2<<<(BATCH * NCHUNK * INNER) / 256, 256, 0, stream>>>(
      delta, u_bf, bmat, cmat, gate_bf, a_log, dvec, Ebuf, mixed);
  // 8. out = mixed @ w_out.T   [2048, 1024] f32   nbx=8, nby=16
  cast_f32_bf16<<<2048, 256, 0, stream>>>(w_out, wsmall_bf, (long)MODEL_DIM * INNER / 4);
  gemm_bt<0><<<8 * 16, 256, 0, stream>>>(
      mixed, wsmall_bf, out, nullptr, 8, 16, MODEL_DIM, INNER);
}

// Round 11
// 1010.437 us; speedup vs baseline: 1.1793x; 1.0190x over previous
//
#include <hip/hip_runtime.h>
#include <hip/hip_bf16.h>

typedef __bf16 bf16_t;
typedef __bf16 bf16x8 __attribute__((ext_vector_type(8)));
typedef float f32x4 __attribute__((ext_vector_type(4)));

#define MODEL_DIM 1024
#define INNER 2048
#define STATE 16
#define BATCH 2
#define SEQ 1024
#define BS (BATCH * SEQ)            // 2048 rows
#define PROJ_N (2 * INNER)          // 4096
#define BCN (INNER * STATE)         // 32768
#define NCHUNK 64
#define CLEN (SEQ / NCHUNK)         // 16

// ---------------------------------------------------------------------------
// async global->LDS, 16B per lane (wave-uniform LDS base, HW adds lane*16)
// ---------------------------------------------------------------------------
__device__ __forceinline__ void load_lds_16B(const void* g, void* l) {
  __builtin_amdgcn_global_load_lds(
      (const __attribute__((address_space(1))) unsigned int*)g,
      (__attribute__((address_space(3))) unsigned int*)l,
      16, 0, 0);
}

// ---------------------------------------------------------------------------
// f32 -> bf16 cast (vectorized, grid-stride). n must be divisible by 4.
// ---------------------------------------------------------------------------
__global__ void cast_f32_bf16(const float* __restrict__ in,
                              bf16_t* __restrict__ out, long n4) {
  long idx = (long)blockIdx.x * blockDim.x + threadIdx.x;
  long stride = (long)gridDim.x * blockDim.x;
  for (long i = idx; i < n4; i += stride) {
    float4 v = ((const float4*)in)[i];
    union { bf16_t b[4]; ushort4 u; } cv;
    cv.b[0] = (bf16_t)v.x; cv.b[1] = (bf16_t)v.y;
    cv.b[2] = (bf16_t)v.z; cv.b[3] = (bf16_t)v.w;
    ((ushort4*)out)[i] = cv.u;
  }
}

// ---------------------------------------------------------------------------
// BIG GEMM, 8-phase 256^2, ROUND-11: SINGLE barrier per phase.
// Round 10's double-barrier lockstep serialized [all-waves ds_read] ->
// [all-waves MFMA]; LDS pipe (~1500-2300 cyc/K-tile at 192KB read volume)
// and MFMA pipe (~2065 cyc/K-tile) never overlapped. Removing barrier1 lets
// waves desync within a phase: early-drained waves MFMA while others read.
// Invariants (re-derived, unchanged from passing rounds 9/10):
//  RAW: stage(p) drained by every wave's own vmcnt(8) at end of p+3 (all
//       waves issue their own part of every stage) + end-of-phase barrier;
//       first read at p+5.
//  WAR: stage(p) targets were last READ in phases < p; reader's ds_reads
//       complete before its MFMA (compiler lgkmcnt) which precedes its
//       end-of-(p-1) barrier; stage(p) issues after that barrier.
// Phase: { ds_reads; stage issue; MFMA (setprio-wrapped); vmcnt(8); barrier;
//          compiler fence }.  Stagger + vmcnt ladder verbatim from round 9:
//   ph1: B(2i+1)s1->buf1  ph2: A(2i+1)s1->buf1  ph3: A(2i+2)s0->buf0
//   ph4: B(2i+2)s0->buf0  ph5: B(2i+2)s1->buf0  ph6: A(2i+2)s1->buf0
//   ph7: A(2i+3)s0->buf1  ph8: B(2i+3)s0->buf1
// Prologue 12 loads + vmcnt(4); peel ladder 8,8,8,4,2,0,0,0.
// Register-fragment reuse (round 10): 24 ds_read_b128/tile/wave.
// LDS buffer stride 16384 ELEMENTS. Swizzle: round-4-proven pair.
// ---------------------------------------------------------------------------
__global__ __launch_bounds__(512, 2)
void gemm_big8(const bf16_t* __restrict__ Ap, const bf16_t* __restrict__ Bp,
               bf16_t* __restrict__ C, int N, int K) {
  __shared__ bf16_t As[2 * 256 * 64];   // 64 KB (buffer stride 16384 elems)
  __shared__ bf16_t Bs[2 * 256 * 64];   // 64 KB
  const int tid = threadIdx.x;
  const int wid = tid >> 6, lane = tid & 63;
  const int wm = wid >> 2, wn = wid & 3;

  // XCD-grouped mapping: 1024 blocks; xcd owns 16 bcol-tiles x 8 brow-tiles
  const int bid = blockIdx.x;
  const int xcd = bid & 7, local = bid >> 3;
  const int bcol = (xcd * 16 + (local >> 3)) * 256;
  const int brow = (local & 7) * 256;

  const int lrow = lane >> 3;                 // 0..7 row within 8-row strip
  const int l7 = lane & 7;
  const int scol = (l7 ^ lrow) * 8;           // pre-swizzled source col (bf16)
  const int r15 = lane & 15, g = lane >> 4;

  const int NT = K >> 6, NI = NT >> 1;

  f32x4 acc[8][4] = {};
  bf16x8 af[4][2], vb0[2][2], vb1[2][2];      // persistent fragments

#define FENCE() asm volatile("" ::: "memory")

  // A set H: rows {j*128 + H*64 + [0,64)}, per wave 8 rows (wid*8+lrow)
#define STAGE_A(BUF, T, H)                                                    \
  {                                                                           \
    _Pragma("unroll") for (int j = 0; j < 2; ++j) {                           \
      const int rs = j * 128 + (H) * 64;                                      \
      load_lds_16B(Ap + (size_t)(brow + rs + wid * 8 + lrow) * K +            \
                       (size_t)(T) * 64 + scol,                               \
                   (void*)(As + (BUF) * 16384 + rs * 64 + wid * 512));        \
    }                                                                         \
  }
  // B set H: rows {q*64 + H*32 + [0,32), q=0..3}; per (j,wid): q=2j+(wid>>2),
  // 8 contiguous rows starting at (wid&3)*8 within the 32-block
#define STAGE_B(BUF, T, H)                                                    \
  {                                                                           \
    _Pragma("unroll") for (int j = 0; j < 2; ++j) {                           \
      const int rs = (2 * j + (wid >> 2)) * 64 + (H) * 32 + (wid & 3) * 8;    \
      load_lds_16B(Bp + (size_t)(bcol + rs + lrow) * K +                      \
                       (size_t)(T) * 64 + scol,                               \
                   (void*)(Bs + (BUF) * 16384 + rs * 64));                    \
    }                                                                         \
  }

#define LOAD_A(BUF, MH)                                                       \
  _Pragma("unroll") for (int m = 0; m < 4; ++m) {                             \
    int arow = wm * 128 + (MH) * 64 + m * 16 + r15;                           \
    _Pragma("unroll") for (int ks = 0; ks < 2; ++ks)                          \
      af[m][ks] = *(const bf16x8*)&As[(BUF) * 16384 + arow * 64 +             \
                                      (((ks * 4 + g) ^ l7) * 8)];             \
  }
#define LOAD_B(BUF, NH, DST)                                                  \
  _Pragma("unroll") for (int n = 0; n < 2; ++n) {                             \
    int brw = wn * 64 + (NH) * 32 + n * 16 + r15;                             \
    _Pragma("unroll") for (int ks = 0; ks < 2; ++ks)                          \
      DST[n][ks] = *(const bf16x8*)&Bs[(BUF) * 16384 + brw * 64 +             \
                                       (((ks * 4 + g) ^ l7) * 8)];            \
  }

  // Single barrier per phase (at end, after vmcnt). ds_reads -> MFMA ordering
  // within a wave is enforced by the compiler's lgkmcnt on the register deps.
#define PHASE(MH, NH, BSEL, LOADS, STAGE_CODE, VMN)                           \
  {                                                                           \
    LOADS;                                                                    \
    STAGE_CODE;                                                               \
    FENCE();                                                                  \
    __builtin_amdgcn_s_setprio(1);                                            \
    _Pragma("unroll") for (int ks = 0; ks < 2; ++ks)                          \
      _Pragma("unroll") for (int m = 0; m < 4; ++m)                           \
        _Pragma("unroll") for (int n = 0; n < 2; ++n)                         \
          acc[(MH) * 4 + m][(NH) * 2 + n] =                                   \
              __builtin_amdgcn_mfma_f32_16x16x32_bf16(                        \
                  af[m][ks], BSEL[n][ks], acc[(MH) * 4 + m][(NH) * 2 + n],    \
                  0, 0, 0);                                                   \
    __builtin_amdgcn_s_setprio(0);                                            \
    asm volatile("s_waitcnt vmcnt(" #VMN ")" ::: "memory");                   \
    __builtin_amdgcn_s_barrier();                                             \
    FENCE();                                                                  \
  }

  // prologue: full tile 0 -> buf0 (8 loads); A(1)s0, B(1)s0 -> buf1 (4 loads)
  STAGE_A(0, 0, 0); STAGE_A(0, 0, 1); STAGE_B(0, 0, 0); STAGE_B(0, 0, 1);
  STAGE_A(1, 1, 0); STAGE_B(1, 1, 0);
  asm volatile("s_waitcnt vmcnt(4)" ::: "memory");
  __builtin_amdgcn_s_barrier();
  FENCE();

  for (int i = 0; i < NI - 1; ++i) {
    const int t1 = 2 * i + 1, t2 = 2 * i + 2, t3 = 2 * i + 3;
    PHASE(0, 0, vb0, {LOAD_A(0, 0); LOAD_B(0, 0, vb0);}, STAGE_B(1, t1, 1), 8);
    PHASE(0, 1, vb1, LOAD_B(0, 1, vb1),                  STAGE_A(1, t1, 1), 8);
    PHASE(1, 0, vb0, LOAD_A(0, 1),                       STAGE_A(0, t2, 0), 8);
    PHASE(1, 1, vb1, ,                                   STAGE_B(0, t2, 0), 8);
    PHASE(0, 0, vb0, {LOAD_A(1, 0); LOAD_B(1, 0, vb0);}, STAGE_B(0, t2, 1), 8);
    PHASE(0, 1, vb1, LOAD_B(1, 1, vb1),                  STAGE_A(0, t2, 1), 8);
    PHASE(1, 0, vb0, LOAD_A(1, 1),                       STAGE_A(1, t3, 0), 8);
    PHASE(1, 1, vb1, ,                                   STAGE_B(1, t3, 0), 8);
  }
  {  // peeled last iteration: tiles NT-2 (buf0), NT-1 (buf1)
    const int tl = NT - 1;
    PHASE(0, 0, vb0, {LOAD_A(0, 0); LOAD_B(0, 0, vb0);}, STAGE_B(1, tl, 1), 8);
    PHASE(0, 1, vb1, LOAD_B(0, 1, vb1),                  STAGE_A(1, tl, 1), 8);
    PHASE(1, 0, vb0, LOAD_A(0, 1),                       , 8);
    PHASE(1, 1, vb1, ,                                   , 4);
    PHASE(0, 0, vb0, {LOAD_A(1, 0); LOAD_B(1, 0, vb0);}, , 2);
    PHASE(0, 1, vb1, LOAD_B(1, 1, vb1),                  , 0);
    PHASE(1, 0, vb0, LOAD_A(1, 1),                       , 0);
    PHASE(1, 1, vb1, ,                                   , 0);
  }
#undef PHASE
#undef LOAD_A
#undef LOAD_B
#undef STAGE_A
#undef STAGE_B
#undef FENCE

  // epilogue: C/D 16x16 layout col=lane&15, row=(lane>>4)*4+j
#pragma unroll
  for (int mf = 0; mf < 8; ++mf) {
#pragma unroll
    for (int nf = 0; nf < 4; ++nf) {
      int col = bcol + wn * 64 + nf * 16 + r15;
#pragma unroll
      for (int j = 0; j < 4; ++j) {
        int row = brow + wm * 128 + mf * 16 + g * 4 + j;
        C[(size_t)row * N + col] = (bf16_t)acc[mf][nf][j];
      }
    }
  }
}

// ---------------------------------------------------------------------------
// BT GEMM (small, round-4 proven): 128x128 tile, BK=64, 4 waves, 16x16x32.
// T2 swizzle (0 conflicts measured) + XCD-grouped grid.
// EPI: 0 = store f32, 1 = softplus(x + bias[col]) f32, 2 = store bf16
// ---------------------------------------------------------------------------
template <int EPI>
__global__ __launch_bounds__(256)
void gemm_bt(const bf16_t* __restrict__ A, const bf16_t* __restrict__ Bt,
             void* __restrict__ C, const float* __restrict__ bias,
             int nbx, int nby, int N, int K) {
  __shared__ bf16_t Ash[128 * 64];
  __shared__ bf16_t Bsh[128 * 64];
  const int tid = threadIdx.x;
  const int wave = tid >> 6, lane = tid & 63;

  const int bid = blockIdx.x;
  const int xcd = bid & 7, local = bid >> 3;
  const int bcol = (xcd * (nbx >> 3) + local / nby) * 128;
  const int brow = (local % nby) * 128;

  const int wr = wave >> 1, wc = wave & 1;

  f32x4 acc[4][4] = {};

  const int seg_base = wave * 4;
  const int lrow = lane >> 3;
  const int scol = ((lane & 7) ^ (lrow & 7)) * 8;
  const int r15 = lane & 15, g = lane >> 4, l7 = lane & 7;

  for (int k0 = 0; k0 < K; k0 += 64) {
#pragma unroll
    for (int c = 0; c < 4; ++c) {
      int seg = seg_base + c;
      int row = seg * 8 + lrow;
      const bf16_t* ga = A + (size_t)(brow + row) * K + k0 + scol;
      load_lds_16B(ga, (void*)(Ash + seg * 512));
      const bf16_t* gb = Bt + (size_t)(bcol + row) * K + k0 + scol;
      load_lds_16B(gb, (void*)(Bsh + seg * 512));
    }
    asm volatile("s_waitcnt vmcnt(0)");
    __syncthreads();

#pragma unroll
    for (int ks = 0; ks < 2; ++ks) {
      bf16x8 af[4], bfr[4];
#pragma unroll
      for (int t = 0; t < 4; ++t) {
        int arow = wr * 64 + t * 16 + r15;
        int brw  = wc * 64 + t * 16 + r15;
        int slot = ((ks * 4 + g) ^ l7) * 8;
        af[t]  = *(const bf16x8*)&Ash[arow * 64 + slot];
        bfr[t] = *(const bf16x8*)&Bsh[brw * 64 + slot];
      }
#pragma unroll
      for (int mt = 0; mt < 4; ++mt)
#pragma unroll
        for (int nt = 0; nt < 4; ++nt)
          acc[mt][nt] = __builtin_amdgcn_mfma_f32_16x16x32_bf16(
              af[mt], bfr[nt], acc[mt][nt], 0, 0, 0);
    }
    __syncthreads();
  }

#pragma unroll
  for (int mt = 0; mt < 4; ++mt) {
#pragma unroll
    for (int nt = 0; nt < 4; ++nt) {
      int col = bcol + wc * 64 + nt * 16 + r15;
#pragma unroll
      for (int j = 0; j < 4; ++j) {
        int row = brow + wr * 64 + mt * 16 + g * 4 + j;
        float v = acc[mt][nt][j];
        size_t idx = (size_t)row * N + col;
        if (EPI == 0) {
          ((float*)C)[idx] = v;
        } else if (EPI == 1) {
          float x = v + bias[col];
          ((float*)C)[idx] = (x > 20.f) ? x : log1pf(__expf(x));
        } else {
          ((bf16_t*)C)[idx] = (bf16_t)v;
        }
      }
    }
  }
}

// ---------------------------------------------------------------------------
// depthwise causal conv(K=4) + bias + SiLU -> u (bf16); also gate = sigmoid
// ---------------------------------------------------------------------------
__global__ __launch_bounds__(256)
void conv_silu(const float* __restrict__ proj, const float* __restrict__ w_conv,
               const float* __restrict__ b_conv, bf16_t* __restrict__ u_bf,
               bf16_t* __restrict__ gate_bf) {
  int idx = blockIdx.x * 256 + threadIdx.x;     // over BATCH*SEQ*INNER
  int i = idx & (INNER - 1);
  int s = (idx >> 11) & (SEQ - 1);
  int b = idx >> 21;
  const float* up = proj + (size_t)b * SEQ * PROJ_N + i;
  float w0 = w_conv[i * 4 + 0], w1 = w_conv[i * 4 + 1];
  float w2 = w_conv[i * 4 + 2], w3 = w_conv[i * 4 + 3];
  float acc = b_conv[i];
  acc += up[(size_t)s * PROJ_N] * w3;
  if (s >= 1) acc += up[(size_t)(s - 1) * PROJ_N] * w2;
  if (s >= 2) acc += up[(size_t)(s - 2) * PROJ_N] * w1;
  if (s >= 3) acc += up[(size_t)(s - 3) * PROJ_N] * w0;
  float u = acc / (1.f + __expf(-acc));  // silu
  u_bf[idx] = (bf16_t)u;
  float gp = up[(size_t)s * PROJ_N + INNER];
  gate_bf[idx] = (bf16_t)(1.f / (1.f + __expf(-gp)));
}

// ---------------------------------------------------------------------------
// chunked selective scan, pass 1
// ---------------------------------------------------------------------------
__global__ __launch_bounds__(256)
void scan_pass1(const float* __restrict__ delta, const bf16_t* __restrict__ u,
                const bf16_t* __restrict__ bmat, const float* __restrict__ a_log,
                float* __restrict__ P, float* __restrict__ E) {
  int t = blockIdx.x * 256 + threadIdx.x;
  int i = t & (INNER - 1);
  int c = (t >> 11) & (NCHUNK - 1);
  int b = t >> 17;
  float an[STATE];
#pragma unroll
  for (int n = 0; n < STATE; ++n) an[n] = -__expf(a_log[i * STATE + n]);
  float st[STATE] = {};
  float dtsum = 0.f;
  size_t base_ch = (size_t)b * SEQ * INNER + i;
  size_t base_bc = (size_t)b * SEQ * BCN + (size_t)i * STATE;
  int s0 = c * CLEN;
  for (int s = s0; s < s0 + CLEN; ++s) {
    float dt = delta[base_ch + (size_t)s * INNER];
    float uv = (float)u[base_ch + (size_t)s * INNER];
    bf16x8 b0 = *(const bf16x8*)&bmat[base_bc + (size_t)s * BCN];
    bf16x8 b1 = *(const bf16x8*)&bmat[base_bc + (size_t)s * BCN + 8];
    float du = dt * uv;
    dtsum += dt;
#pragma unroll
    for (int n = 0; n < 8; ++n)
      st[n] = __expf(dt * an[n]) * st[n] + du * (float)b0[n];
#pragma unroll
    for (int n = 0; n < 8; ++n)
      st[8 + n] = __expf(dt * an[8 + n]) * st[8 + n] + du * (float)b1[n];
  }
  size_t pe = ((size_t)(b * NCHUNK + c) * INNER + i) * STATE;
#pragma unroll
  for (int q = 0; q < 4; ++q) {
    f32x4 vp = {__expf(dtsum * an[q * 4]), __expf(dtsum * an[q * 4 + 1]),
                __expf(dtsum * an[q * 4 + 2]), __expf(dtsum * an[q * 4 + 3])};
    *(f32x4*)&P[pe + q * 4] = vp;
    f32x4 ve = {st[q * 4], st[q * 4 + 1], st[q * 4 + 2], st[q * 4 + 3]};
    *(f32x4*)&E[pe + q * 4] = ve;
  }
}

// ---------------------------------------------------------------------------
// chunked scan, middle: sequential combine over chunks per (b,i,n)
// ---------------------------------------------------------------------------
__global__ __launch_bounds__(256)
void scan_mid(const float* __restrict__ P, float* __restrict__ E) {
  int gi = blockIdx.x * 256 + threadIdx.x;
  int n = gi & (STATE - 1);
  int i = (gi >> 4) & (INNER - 1);
  int b = gi >> 15;
  float H = 0.f;
  size_t stride = (size_t)INNER * STATE;
  size_t idx = (size_t)b * NCHUNK * stride + (size_t)i * STATE + n;
  for (int c = 0; c < NCHUNK; ++c) {
    float p = P[idx];
    float e = E[idx];
    E[idx] = H;
    H = p * H + e;
    idx += stride;
  }
}

// ---------------------------------------------------------------------------
// chunked scan, pass 2
// ---------------------------------------------------------------------------
__global__ __launch_bounds__(256)
void scan_pass2(const float* __restrict__ delta, const bf16_t* __restrict__ u,
                const bf16_t* __restrict__ bmat, const bf16_t* __restrict__ cmat,
                const bf16_t* __restrict__ gate, const float* __restrict__ a_log,
                const float* __restrict__ dvec, const float* __restrict__ E,
                bf16_t* __restrict__ mixed) {
  int t = blockIdx.x * 256 + threadIdx.x;
  int i = t & (INNER - 1);
  int c = (t >> 11) & (NCHUNK - 1);
  int b = t >> 17;
  float an[STATE];
#pragma unroll
  for (int n = 0; n < STATE; ++n) an[n] = -__expf(a_log[i * STATE + n]);
  float st[STATE];
  size_t pe = ((size_t)(b * NCHUNK + c) * INNER + i) * STATE;
#pragma unroll
  for (int q = 0; q < 4; ++q) {
    f32x4 v = *(const f32x4*)&E[pe + q * 4];
    st[q * 4] = v[0]; st[q * 4 + 1] = v[1]; st[q * 4 + 2] = v[2]; st[q * 4 + 3] = v[3];
  }
  float dd = dvec[i];
  size_t base_ch = (size_t)b * SEQ * INNER + i;
  size_t base_bc = (size_t)b * SEQ * BCN + (size_t)i * STATE;
  int s0 = c * CLEN;
  for (int s = s0; s < s0 + CLEN; ++s) {
    float dt = delta[base_ch + (size_t)s * INNER];
    float uv = (float)u[base_ch + (size_t)s * INNER];
    bf16x8 b0 = *(const bf16x8*)&bmat[base_bc + (size_t)s * BCN];
    bf16x8 b1 = *(const bf16x8*)&bmat[base_bc + (size_t)s * BCN + 8];
    bf16x8 c0 = *(const bf16x8*)&cmat[base_bc + (size_t)s * BCN];
    bf16x8 c1 = *(const bf16x8*)&cmat[base_bc + (size_t)s * BCN + 8];
    float du = dt * uv;
    float y = 0.f;
#pragma unroll
    for (int n = 0; n < 8; ++n) {
      st[n] = __expf(dt * an[n]) * st[n] + du * (float)b0[n];
      y += (float)c0[n] * st[n];
    }
#pragma unroll
    for (int n = 0; n < 8; ++n) {
      st[8 + n] = __expf(dt * an[8 + n]) * st[8 + n] + du * (float)b1[n];
      y += (float)c1[n] * st[8 + n];
    }
    float g = (float)gate[base_ch + (size_t)s * INNER];
    mixed[base_ch + (size_t)s * INNER] = (bf16_t)((y + dd * uv) * g);
  }
}

// ---------------------------------------------------------------------------
extern "C" void kernel_launch(void* const* d_in, const int* in_sizes, int n_in,
                              void* d_out, int out_size, void* d_ws, size_t ws_size,
                              hipStream_t stream) {
  const float* hidden = (const float*)d_in[0];
  const float* w_in   = (const float*)d_in[1];
  const float* w_conv = (const float*)d_in[2];
  const float* b_conv = (const float*)d_in[3];
  const float* w_dt   = (const float*)d_in[4];
  const float* b_dt   = (const float*)d_in[5];
  const float* w_b    = (const float*)d_in[6];
  const float* w_c    = (const float*)d_in[7];
  const float* w_out  = (const float*)d_in[8];
  const float* a_log  = (const float*)d_in[9];
  const float* dvec   = (const float*)d_in[10];
  float* out = (float*)d_out;

  char* ws = (char*)d_ws;
  bf16_t* hidden_bf = (bf16_t*)ws; ws += (size_t)BS * MODEL_DIM * 2;       // 4MB
  bf16_t* wsmall_bf = (bf16_t*)ws; ws += (size_t)PROJ_N * MODEL_DIM * 2;   // 8MB
  float*  proj      = (float*)ws;  ws += (size_t)BS * PROJ_N * 4;          // 32MB
  bf16_t* u_bf      = (bf16_t*)ws; ws += (size_t)BS * INNER * 2;           // 8MB
  bf16_t* gate_bf   = (bf16_t*)ws; ws += (size_t)BS * INNER * 2;           // 8MB
  float*  delta     = (float*)ws;  ws += (size_t)BS * INNER * 4;           // 16MB
  bf16_t* wbig_bf   = (bf16_t*)ws; ws += (size_t)BCN * INNER * 2;          // 128MB
  bf16_t* bmat      = (bf16_t*)ws; ws += (size_t)BS * BCN * 2;             // 128MB
  bf16_t* cmat      = (bf16_t*)ws; ws += (size_t)BS * BCN * 2;             // 128MB
  bf16_t* mixed     = (bf16_t*)ws; ws += (size_t)BS * INNER * 2;           // 8MB
  float* Pbuf = (float*)wbig_bf;                                           // 16.8MB
  float* Ebuf = Pbuf + (size_t)BATCH * NCHUNK * INNER * STATE;             // 16.8MB

  // 1. cast hidden + w_in
  cast_f32_bf16<<<2048, 256, 0, stream>>>(hidden, hidden_bf, (long)BS * MODEL_DIM / 4);
  cast_f32_bf16<<<2048, 256, 0, stream>>>(w_in, wsmall_bf, (long)PROJ_N * MODEL_DIM / 4);
  // 2. proj = hidden @ w_in.T   [2048, 4096]   nbx=32, nby=16
  gemm_bt<0><<<32 * 16, 256, 0, stream>>>(
      hidden_bf, wsmall_bf, proj, nullptr, 32, 16, PROJ_N, MODEL_DIM);
  // 3. conv + silu -> u (bf16); gate = sigmoid (bf16)
  conv_silu<<<(BATCH * SEQ * INNER) / 256, 256, 0, stream>>>(proj, w_conv, b_conv, u_bf, gate_bf);
  // 4. delta = softplus(u @ w_dt.T + b_dt)   [2048, 2048] f32   nbx=16, nby=16
  cast_f32_bf16<<<2048, 256, 0, stream>>>(w_dt, wsmall_bf, (long)INNER * INNER / 4);
  gemm_bt<1><<<16 * 16, 256, 0, stream>>>(
      u_bf, wsmall_bf, delta, b_dt, 16, 16, INNER, INNER);
  // 5. bmat = u @ w_b.T   [2048, 32768] bf16  (8-phase 256^2 kernel)
  cast_f32_bf16<<<2048, 256, 0, stream>>>(w_b, wbig_bf, (long)BCN * INNER / 4);
  gemm_big8<<<1024, 512, 0, stream>>>(u_bf, wbig_bf, bmat, BCN, INNER);
  // 6. cmat = u @ w_c.T
  cast_f32_bf16<<<2048, 256, 0, stream>>>(w_c, wbig_bf, (long)BCN * INNER / 4);
  gemm_big8<<<1024, 512, 0, stream>>>(u_bf, wbig_bf, cmat, BCN, INNER);
  // 7. chunked scan (P/E alias wbig_bf which is dead now)
  scan_pass1<<<(BATCH * NCHUNK * INNER) / 256, 256, 0, stream>>>(
      delta, u_bf, bmat, a_log, Pbuf, Ebuf);
  scan_mid<<<(BATCH * INNER * STATE) / 256, 256, 0, stream>>>(Pbuf, Ebuf);
  scan_pass2<<<(BATCH * NCHUNK * INNER) / 256, 256, 0, stream>>>(
      delta, u_bf, bmat, cmat, gate_bf, a_log, dvec, Ebuf, mixed);
  // 8. out = mixed @ w_out.T   [2048, 1024] f32   nbx=8, nby=16
  cast_f32_bf16<<<2048, 256, 0, stream>>>(w_out, wsmall_bf, (long)MODEL_DIM * INNER / 4);
  gemm_bt<0><<<8 * 16, 256, 0, stream>>>(
      mixed, wsmall_bf, out, nullptr, 8, 16, MODEL_DIM, INNER);
}

// Round 12
// 1009.444 us; speedup vs baseline: 1.1805x; 1.0010x over previous
//
#include <hip/hip_runtime.h>
#include <hip/hip_bf16.h>

typedef __bf16 bf16_t;
typedef __bf16 bf16x8 __attribute__((ext_vector_type(8)));
typedef float f32x4 __attribute__((ext_vector_type(4)));

#define MODEL_DIM 1024
#define INNER 2048
#define STATE 16
#define BATCH 2
#define SEQ 1024
#define BS (BATCH * SEQ)            // 2048 rows
#define PROJ_N (2 * INNER)          // 4096
#define BCN (INNER * STATE)         // 32768
#define NCHUNK 64
#define CLEN (SEQ / NCHUNK)         // 16

// ---------------------------------------------------------------------------
// async global->LDS, 16B per lane (wave-uniform LDS base, HW adds lane*16)
// ---------------------------------------------------------------------------
__device__ __forceinline__ void load_lds_16B(const void* g, void* l) {
  __builtin_amdgcn_global_load_lds(
      (const __attribute__((address_space(1))) unsigned int*)g,
      (__attribute__((address_space(3))) unsigned int*)l,
      16, 0, 0);
}

// ---------------------------------------------------------------------------
// f32 -> bf16 cast (vectorized, grid-stride). n must be divisible by 4.
// ---------------------------------------------------------------------------
__global__ void cast_f32_bf16(const float* __restrict__ in,
                              bf16_t* __restrict__ out, long n4) {
  long idx = (long)blockIdx.x * blockDim.x + threadIdx.x;
  long stride = (long)gridDim.x * blockDim.x;
  for (long i = idx; i < n4; i += stride) {
    float4 v = ((const float4*)in)[i];
    union { bf16_t b[4]; ushort4 u; } cv;
    cv.b[0] = (bf16_t)v.x; cv.b[1] = (bf16_t)v.y;
    cv.b[2] = (bf16_t)v.z; cv.b[3] = (bf16_t)v.w;
    ((ushort4*)out)[i] = cv.u;
  }
}

// ---------------------------------------------------------------------------
// BIG GEMM, 8-phase 256^2, ROUND-12: m201-style vmcnt cadence (waits only at
// phases 4 and 8, never per-phase). Round 11 waited vmcnt(8) at EVERY phase
// end = 8 rendezvous points/iter; the residual ~3200 cyc/K-tile stall is
// there. New: vmcnt(4) at ph4 and ph8 only; 12 loads in flight steady-state.
//
// Residency re-derivation (reads: ph1<-prevPh3/4, ph2<-prevPh5, ph3<-prevPh6,
// ph5<-prevPh7/8, ph6<-thisPh1, ph7<-thisPh2; 2 loads/stage):
//  vmcnt(4)@ph4: newest-4 = ph3,ph4 stages -> prevPh7/8 + thisPh1/2 drained
//                => ph5, ph6, ph7 reads safe.
//  vmcnt(4)@ph8: newest-4 = ph7,ph8 stages -> everything <=ph6 drained
//                => next ph1, ph2, ph3 reads safe.
// Peel (stages only ph1,ph2): vmcnt(2)@ph4 (drains peel-ph1 for ph6 read,
// prev ph7/8 for ph5), vmcnt(0)@ph5 (drains peel-ph2 for ph7).
// Prologue: 12 loads + vmcnt(4) (drains all 8 buf0 ops). Everything else
// (stagger, reads, register-fragment reuse, single barrier/phase, fences,
// swizzle, 16384-elem LDS stride) identical to passing round 11.
//   ph1: B(2i+1)s1->buf1  ph2: A(2i+1)s1->buf1  ph3: A(2i+2)s0->buf0
//   ph4: B(2i+2)s0->buf0  ph5: B(2i+2)s1->buf0  ph6: A(2i+2)s1->buf0
//   ph7: A(2i+3)s0->buf1  ph8: B(2i+3)s0->buf1
// ---------------------------------------------------------------------------
__global__ __launch_bounds__(512, 2)
void gemm_big8(const bf16_t* __restrict__ Ap, const bf16_t* __restrict__ Bp,
               bf16_t* __restrict__ C, int N, int K) {
  __shared__ bf16_t As[2 * 256 * 64];   // 64 KB (buffer stride 16384 elems)
  __shared__ bf16_t Bs[2 * 256 * 64];   // 64 KB
  const int tid = threadIdx.x;
  const int wid = tid >> 6, lane = tid & 63;
  const int wm = wid >> 2, wn = wid & 3;

  // XCD-grouped mapping: 1024 blocks; xcd owns 16 bcol-tiles x 8 brow-tiles
  const int bid = blockIdx.x;
  const int xcd = bid & 7, local = bid >> 3;
  const int bcol = (xcd * 16 + (local >> 3)) * 256;
  const int brow = (local & 7) * 256;

  const int lrow = lane >> 3;                 // 0..7 row within 8-row strip
  const int l7 = lane & 7;
  const int scol = (l7 ^ lrow) * 8;           // pre-swizzled source col (bf16)
  const int r15 = lane & 15, g = lane >> 4;

  const int NT = K >> 6, NI = NT >> 1;

  f32x4 acc[8][4] = {};
  bf16x8 af[4][2], vb0[2][2], vb1[2][2];      // persistent fragments

#define FENCE() asm volatile("" ::: "memory")
#define VM_WAIT(n) asm volatile("s_waitcnt vmcnt(" #n ")" ::: "memory")

  // A set H: rows {j*128 + H*64 + [0,64)}, per wave 8 rows (wid*8+lrow)
#define STAGE_A(BUF, T, H)                                                    \
  {                                                                           \
    _Pragma("unroll") for (int j = 0; j < 2; ++j) {                           \
      const int rs = j * 128 + (H) * 64;                                      \
      load_lds_16B(Ap + (size_t)(brow + rs + wid * 8 + lrow) * K +            \
                       (size_t)(T) * 64 + scol,                               \
                   (void*)(As + (BUF) * 16384 + rs * 64 + wid * 512));        \
    }                                                                         \
  }
  // B set H: rows {q*64 + H*32 + [0,32), q=0..3}; per (j,wid): q=2j+(wid>>2),
  // 8 contiguous rows starting at (wid&3)*8 within the 32-block
#define STAGE_B(BUF, T, H)                                                    \
  {                                                                           \
    _Pragma("unroll") for (int j = 0; j < 2; ++j) {                           \
      const int rs = (2 * j + (wid >> 2)) * 64 + (H) * 32 + (wid & 3) * 8;    \
      load_lds_16B(Bp + (size_t)(bcol + rs + lrow) * K +                      \
                       (size_t)(T) * 64 + scol,                               \
                   (void*)(Bs + (BUF) * 16384 + rs * 64));                    \
    }                                                                         \
  }

#define LOAD_A(BUF, MH)                                                       \
  _Pragma("unroll") for (int m = 0; m < 4; ++m) {                             \
    int arow = wm * 128 + (MH) * 64 + m * 16 + r15;                           \
    _Pragma("unroll") for (int ks = 0; ks < 2; ++ks)                          \
      af[m][ks] = *(const bf16x8*)&As[(BUF) * 16384 + arow * 64 +             \
                                      (((ks * 4 + g) ^ l7) * 8)];             \
  }
#define LOAD_B(BUF, NH, DST)                                                  \
  _Pragma("unroll") for (int n = 0; n < 2; ++n) {                             \
    int brw = wn * 64 + (NH) * 32 + n * 16 + r15;                             \
    _Pragma("unroll") for (int ks = 0; ks < 2; ++ks)                          \
      DST[n][ks] = *(const bf16x8*)&Bs[(BUF) * 16384 + brw * 64 +             \
                                       (((ks * 4 + g) ^ l7) * 8)];            \
  }

  // Single barrier per phase; vmcnt only where WAITC specifies.
#define PHASE(MH, NH, BSEL, LOADS, STAGE_CODE, WAITC)                         \
  {                                                                           \
    LOADS;                                                                    \
    STAGE_CODE;                                                               \
    FENCE();                                                                  \
    __builtin_amdgcn_s_setprio(1);                                            \
    _Pragma("unroll") for (int ks = 0; ks < 2; ++ks)                          \
      _Pragma("unroll") for (int m = 0; m < 4; ++m)                           \
        _Pragma("unroll") for (int n = 0; n < 2; ++n)                         \
          acc[(MH) * 4 + m][(NH) * 2 + n] =                                   \
              __builtin_amdgcn_mfma_f32_16x16x32_bf16(                        \
                  af[m][ks], BSEL[n][ks], acc[(MH) * 4 + m][(NH) * 2 + n],    \
                  0, 0, 0);                                                   \
    __builtin_amdgcn_s_setprio(0);                                            \
    WAITC;                                                                    \
    FENCE();                                                                  \
    __builtin_amdgcn_s_barrier();                                             \
    FENCE();                                                                  \
  }

  // prologue: full tile 0 -> buf0 (8 loads); A(1)s0, B(1)s0 -> buf1 (4 loads)
  STAGE_A(0, 0, 0); STAGE_A(0, 0, 1); STAGE_B(0, 0, 0); STAGE_B(0, 0, 1);
  STAGE_A(1, 1, 0); STAGE_B(1, 1, 0);
  VM_WAIT(4);
  __builtin_amdgcn_s_barrier();
  FENCE();

  for (int i = 0; i < NI - 1; ++i) {
    const int t1 = 2 * i + 1, t2 = 2 * i + 2, t3 = 2 * i + 3;
    PHASE(0, 0, vb0, {LOAD_A(0, 0); LOAD_B(0, 0, vb0);}, STAGE_B(1, t1, 1), );
    PHASE(0, 1, vb1, LOAD_B(0, 1, vb1),                  STAGE_A(1, t1, 1), );
    PHASE(1, 0, vb0, LOAD_A(0, 1),                       STAGE_A(0, t2, 0), );
    PHASE(1, 1, vb1, ,                                   STAGE_B(0, t2, 0), VM_WAIT(4));
    PHASE(0, 0, vb0, {LOAD_A(1, 0); LOAD_B(1, 0, vb0);}, STAGE_B(0, t2, 1), );
    PHASE(0, 1, vb1, LOAD_B(1, 1, vb1),                  STAGE_A(0, t2, 1), );
    PHASE(1, 0, vb0, LOAD_A(1, 1),                       STAGE_A(1, t3, 0), );
    PHASE(1, 1, vb1, ,                                   STAGE_B(1, t3, 0), VM_WAIT(4));
  }
  {  // peeled last iteration: tiles NT-2 (buf0), NT-1 (buf1)
    const int tl = NT - 1;
    PHASE(0, 0, vb0, {LOAD_A(0, 0); LOAD_B(0, 0, vb0);}, STAGE_B(1, tl, 1), );
    PHASE(0, 1, vb1, LOAD_B(0, 1, vb1),                  STAGE_A(1, tl, 1), );
    PHASE(1, 0, vb0, LOAD_A(0, 1),                       , );
    PHASE(1, 1, vb1, ,                                   , VM_WAIT(2));
    PHASE(0, 0, vb0, {LOAD_A(1, 0); LOAD_B(1, 0, vb0);}, , VM_WAIT(0));
    PHASE(0, 1, vb1, LOAD_B(1, 1, vb1),                  , );
    PHASE(1, 0, vb0, LOAD_A(1, 1),                       , );
    PHASE(1, 1, vb1, ,                                   , );
  }
#undef PHASE
#undef LOAD_A
#undef LOAD_B
#undef STAGE_A
#undef STAGE_B
#undef VM_WAIT
#undef FENCE

  // epilogue: C/D 16x16 layout col=lane&15, row=(lane>>4)*4+j
#pragma unroll
  for (int mf = 0; mf < 8; ++mf) {
#pragma unroll
    for (int nf = 0; nf < 4; ++nf) {
      int col = bcol + wn * 64 + nf * 16 + r15;
#pragma unroll
      for (int j = 0; j < 4; ++j) {
        int row = brow + wm * 128 + mf * 16 + g * 4 + j;
        C[(size_t)row * N + col] = (bf16_t)acc[mf][nf][j];
      }
    }
  }
}

// ---------------------------------------------------------------------------
// BT GEMM (small, round-4 proven): 128x128 tile, BK=64, 4 waves, 16x16x32.
// T2 swizzle (0 conflicts measured) + XCD-grouped grid.
// EPI: 0 = store f32, 1 = softplus(x + bias[col]) f32, 2 = store bf16
// ---------------------------------------------------------------------------
template <int EPI>
__global__ __launch_bounds__(256)
void gemm_bt(const bf16_t* __restrict__ A, const bf16_t* __restrict__ Bt,
             void* __restrict__ C, const float* __restrict__ bias,
             int nbx, int nby, int N, int K) {
  __shared__ bf16_t Ash[128 * 64];
  __shared__ bf16_t Bsh[128 * 64];
  const int tid = threadIdx.x;
  const int wave = tid >> 6, lane = tid & 63;

  const int bid = blockIdx.x;
  const int xcd = bid & 7, local = bid >> 3;
  const int bcol = (xcd * (nbx >> 3) + local / nby) * 128;
  const int brow = (local % nby) * 128;

  const int wr = wave >> 1, wc = wave & 1;

  f32x4 acc[4][4] = {};

  const int seg_base = wave * 4;
  const int lrow = lane >> 3;
  const int scol = ((lane & 7) ^ (lrow & 7)) * 8;
  const int r15 = lane & 15, g = lane >> 4, l7 = lane & 7;

  for (int k0 = 0; k0 < K; k0 += 64) {
#pragma unroll
    for (int c = 0; c < 4; ++c) {
      int seg = seg_base + c;
      int row = seg * 8 + lrow;
      const bf16_t* ga = A + (size_t)(brow + row) * K + k0 + scol;
      load_lds_16B(ga, (void*)(Ash + seg * 512));
      const bf16_t* gb = Bt + (size_t)(bcol + row) * K + k0 + scol;
      load_lds_16B(gb, (void*)(Bsh + seg * 512));
    }
    asm volatile("s_waitcnt vmcnt(0)");
    __syncthreads();

#pragma unroll
    for (int ks = 0; ks < 2; ++ks) {
      bf16x8 af[4], bfr[4];
#pragma unroll
      for (int t = 0; t < 4; ++t) {
        int arow = wr * 64 + t * 16 + r15;
        int brw  = wc * 64 + t * 16 + r15;
        int slot = ((ks * 4 + g) ^ l7) * 8;
        af[t]  = *(const bf16x8*)&Ash[arow * 64 + slot];
        bfr[t] = *(const bf16x8*)&Bsh[brw * 64 + slot];
      }
#pragma unroll
      for (int mt = 0; mt < 4; ++mt)
#pragma unroll
        for (int nt = 0; nt < 4; ++nt)
          acc[mt][nt] = __builtin_amdgcn_mfma_f32_16x16x32_bf16(
              af[mt], bfr[nt], acc[mt][nt], 0, 0, 0);
    }
    __syncthreads();
  }

#pragma unroll
  for (int mt = 0; mt < 4; ++mt) {
#pragma unroll
    for (int nt = 0; nt < 4; ++nt) {
      int col = bcol + wc * 64 + nt * 16 + r15;
#pragma unroll
      for (int j = 0; j < 4; ++j) {
        int row = brow + wr * 64 + mt * 16 + g * 4 + j;
        float v = acc[mt][nt][j];
        size_t idx = (size_t)row * N + col;
        if (EPI == 0) {
          ((float*)C)[idx] = v;
        } else if (EPI == 1) {
          float x = v + bias[col];
          ((float*)C)[idx] = (x > 20.f) ? x : log1pf(__expf(x));
        } else {
          ((bf16_t*)C)[idx] = (bf16_t)v;
        }
      }
    }
  }
}

// ---------------------------------------------------------------------------
// depthwise causal conv(K=4) + bias + SiLU -> u (bf16); also gate = sigmoid
// ---------------------------------------------------------------------------
__global__ __launch_bounds__(256)
void conv_silu(const float* __restrict__ proj, const float* __restrict__ w_conv,
               const float* __restrict__ b_conv, bf16_t* __restrict__ u_bf,
               bf16_t* __restrict__ gate_bf) {
  int idx = blockIdx.x * 256 + threadIdx.x;     // over BATCH*SEQ*INNER
  int i = idx & (INNER - 1);
  int s = (idx >> 11) & (SEQ - 1);
  int b = idx >> 21;
  const float* up = proj + (size_t)b * SEQ * PROJ_N + i;
  float w0 = w_conv[i * 4 + 0], w1 = w_conv[i * 4 + 1];
  float w2 = w_conv[i * 4 + 2], w3 = w_conv[i * 4 + 3];
  float acc = b_conv[i];
  acc += up[(size_t)s * PROJ_N] * w3;
  if (s >= 1) acc += up[(size_t)(s - 1) * PROJ_N] * w2;
  if (s >= 2) acc += up[(size_t)(s - 2) * PROJ_N] * w1;
  if (s >= 3) acc += up[(size_t)(s - 3) * PROJ_N] * w0;
  float u = acc / (1.f + __expf(-acc));  // silu
  u_bf[idx] = (bf16_t)u;
  float gp = up[(size_t)s * PROJ_N + INNER];
  gate_bf[idx] = (bf16_t)(1.f / (1.f + __expf(-gp)));
}

// ---------------------------------------------------------------------------
// chunked selective scan, pass 1
// ---------------------------------------------------------------------------
__global__ __launch_bounds__(256)
void scan_pass1(const float* __restrict__ delta, const bf16_t* __restrict__ u,
                const bf16_t* __restrict__ bmat, const float* __restrict__ a_log,
                float* __restrict__ P, float* __restrict__ E) {
  int t = blockIdx.x * 256 + threadIdx.x;
  int i = t & (INNER - 1);
  int c = (t >> 11) & (NCHUNK - 1);
  int b = t >> 17;
  float an[STATE];
#pragma unroll
  for (int n = 0; n < STATE; ++n) an[n] = -__expf(a_log[i * STATE + n]);
  float st[STATE] = {};
  float dtsum = 0.f;
  size_t base_ch = (size_t)b * SEQ * INNER + i;
  size_t base_bc = (size_t)b * SEQ * BCN + (size_t)i * STATE;
  int s0 = c * CLEN;
  for (int s = s0; s < s0 + CLEN; ++s) {
    float dt = delta[base_ch + (size_t)s * INNER];
    float uv = (float)u[base_ch + (size_t)s * INNER];
    bf16x8 b0 = *(const bf16x8*)&bmat[base_bc + (size_t)s * BCN];
    bf16x8 b1 = *(const bf16x8*)&bmat[base_bc + (size_t)s * BCN + 8];
    float du = dt * uv;
    dtsum += dt;
#pragma unroll
    for (int n = 0; n < 8; ++n)
      st[n] = __expf(dt * an[n]) * st[n] + du * (float)b0[n];
#pragma unroll
    for (int n = 0; n < 8; ++n)
      st[8 + n] = __expf(dt * an[8 + n]) * st[8 + n] + du * (float)b1[n];
  }
  size_t pe = ((size_t)(b * NCHUNK + c) * INNER + i) * STATE;
#pragma unroll
  for (int q = 0; q < 4; ++q) {
    f32x4 vp = {__expf(dtsum * an[q * 4]), __expf(dtsum * an[q * 4 + 1]),
                __expf(dtsum * an[q * 4 + 2]), __expf(dtsum * an[q * 4 + 3])};
    *(f32x4*)&P[pe + q * 4] = vp;
    f32x4 ve = {st[q * 4], st[q * 4 + 1], st[q * 4 + 2], st[q * 4 + 3]};
    *(f32x4*)&E[pe + q * 4] = ve;
  }
}

// ---------------------------------------------------------------------------
// chunked scan, middle: sequential combine over chunks per (b,i,n)
// ---------------------------------------------------------------------------
__global__ __launch_bounds__(256)
void scan_mid(const float* __restrict__ P, float* __restrict__ E) {
  int gi = blockIdx.x * 256 + threadIdx.x;
  int n = gi & (STATE - 1);
  int i = (gi >> 4) & (INNER - 1);
  int b = gi >> 15;
  float H = 0.f;
  size_t stride = (size_t)INNER * STATE;
  size_t idx = (size_t)b * NCHUNK * stride + (size_t)i * STATE + n;
  for (int c = 0; c < NCHUNK; ++c) {
    float p = P[idx];
    float e = E[idx];
    E[idx] = H;
    H = p * H + e;
    idx += stride;
  }
}

// ---------------------------------------------------------------------------
// chunked scan, pass 2
// ---------------------------------------------------------------------------
__global__ __launch_bounds__(256)
void scan_pass2(const float* __restrict__ delta, const bf16_t* __restrict__ u,
                const bf16_t* __restrict__ bmat, const bf16_t* __restrict__ cmat,
                const bf16_t* __restrict__ gate, const float* __restrict__ a_log,
                const float* __restrict__ dvec, const float* __restrict__ E,
                bf16_t* __restrict__ mixed) {
  int t = blockIdx.x * 256 + threadIdx.x;
  int i = t & (INNER - 1);
  int c = (t >> 11) & (NCHUNK - 1);
  int b = t >> 17;
  float an[STATE];
#pragma unroll
  for (int n = 0; n < STATE; ++n) an[n] = -__expf(a_log[i * STATE + n]);
  float st[STATE];
  size_t pe = ((size_t)(b * NCHUNK + c) * INNER + i) * STATE;
#pragma unroll
  for (int q = 0; q < 4; ++q) {
    f32x4 v = *(const f32x4*)&E[pe + q * 4];
    st[q * 4] = v[0]; st[q * 4 + 1] = v[1]; st[q * 4 + 2] = v[2]; st[q * 4 + 3] = v[3];
  }
  float dd = dvec[i];
  size_t base_ch = (size_t)b * SEQ * INNER + i;
  size_t base_bc = (size_t)b * SEQ * BCN + (size_t)i * STATE;
  int s0 = c * CLEN;
  for (int s = s0; s < s0 + CLEN; ++s) {
    float dt = delta[base_ch + (size_t)s * INNER];
    float uv = (float)u[base_ch + (size_t)s * INNER];
    bf16x8 b0 = *(const bf16x8*)&bmat[base_bc + (size_t)s * BCN];
    bf16x8 b1 = *(const bf16x8*)&bmat[base_bc + (size_t)s * BCN + 8];
    bf16x8 c0 = *(const bf16x8*)&cmat[base_bc + (size_t)s * BCN];
    bf16x8 c1 = *(const bf16x8*)&cmat[base_bc + (size_t)s * BCN + 8];
    float du = dt * uv;
    float y = 0.f;
#pragma unroll
    for (int n = 0; n < 8; ++n) {
      st[n] = __expf(dt * an[n]) * st[n] + du * (float)b0[n];
      y += (float)c0[n] * st[n];
    }
#pragma unroll
    for (int n = 0; n < 8; ++n) {
      st[8 + n] = __expf(dt * an[8 + n]) * st[8 + n] + du * (float)b1[n];
      y += (float)c1[n] * st[8 + n];
    }
    float g = (float)gate[base_ch + (size_t)s * INNER];
    mixed[base_ch + (size_t)s * INNER] = (bf16_t)((y + dd * uv) * g);
  }
}

// ---------------------------------------------------------------------------
extern "C" void kernel_launch(void* const* d_in, const int* in_sizes, int n_in,
                              void* d_out, int out_size, void* d_ws, size_t ws_size,
                              hipStream_t stream) {
  const float* hidden = (const float*)d_in[0];
  const float* w_in   = (const float*)d_in[1];
  const float* w_conv = (const float*)d_in[2];
  const float* b_conv = (const float*)d_in[3];
  const float* w_dt   = (const float*)d_in[4];
  const float* b_dt   = (const float*)d_in[5];
  const float* w_b    = (const float*)d_in[6];
  const float* w_c    = (const float*)d_in[7];
  const float* w_out  = (const float*)d_in[8];
  const float* a_log  = (const float*)d_in[9];
  const float* dvec   = (const float*)d_in[10];
  float* out = (float*)d_out;

  char* ws = (char*)d_ws;
  bf16_t* hidden_bf = (bf16_t*)ws; ws += (size_t)BS * MODEL_DIM * 2;       // 4MB
  bf16_t* wsmall_bf = (bf16_t*)ws; ws += (size_t)PROJ_N * MODEL_DIM * 2;   // 8MB
  float*  proj      = (float*)ws;  ws += (size_t)BS * PROJ_N * 4;          // 32MB
  bf16_t* u_bf      = (bf16_t*)ws; ws += (size_t)BS * INNER * 2;           // 8MB
  bf16_t* gate_bf   = (bf16_t*)ws; ws += (size_t)BS * INNER * 2;           // 8MB
  float*  delta     = (float*)ws;  ws += (size_t)BS * INNER * 4;           // 16MB
  bf16_t* wbig_bf   = (bf16_t*)ws; ws += (size_t)BCN * INNER * 2;          // 128MB
  bf16_t* bmat      = (bf16_t*)ws; ws += (size_t)BS * BCN * 2;             // 128MB
  bf16_t* cmat      = (bf16_t*)ws; ws += (size_t)BS * BCN * 2;             // 128MB
  bf16_t* mixed     = (bf16_t*)ws; ws += (size_t)BS * INNER * 2;           // 8MB
  float* Pbuf = (float*)wbig_bf;                                           // 16.8MB
  float* Ebuf = Pbuf + (size_t)BATCH * NCHUNK * INNER * STATE;             // 16.8MB

  // 1. cast hidden + w_in
  cast_f32_bf16<<<2048, 256, 0, stream>>>(hidden, hidden_bf, (long)BS * MODEL_DIM / 4);
  cast_f32_bf16<<<2048, 256, 0, stream>>>(w_in, wsmall_bf, (long)PROJ_N * MODEL_DIM / 4);
  // 2. proj = hidden @ w_in.T   [2048, 4096]   nbx=32, nby=16
  gemm_bt<0><<<32 * 16, 256, 0, stream>>>(
      hidden_bf, wsmall_bf, proj, nullptr, 32, 16, PROJ_N, MODEL_DIM);
  // 3. conv + silu -> u (bf16); gate = sigmoid (bf16)
  conv_silu<<<(BATCH * SEQ * INNER) / 256, 256, 0, stream>>>(proj, w_conv, b_conv, u_bf, gate_bf);
  // 4. delta = softplus(u @ w_dt.T + b_dt)   [2048, 2048] f32   nbx=16, nby=16
  cast_f32_bf16<<<2048, 256, 0, stream>>>(w_dt, wsmall_bf, (long)INNER * INNER / 4);
  gemm_bt<1><<<16 * 16, 256, 0, stream>>>(
      u_bf, wsmall_bf, delta, b_dt, 16, 16, INNER, INNER);
  // 5. bmat = u @ w_b.T   [2048, 32768] bf16  (8-phase 256^2 kernel)
  cast_f32_bf16<<<2048, 256, 0, stream>>>(w_b, wbig_bf, (long)BCN * INNER / 4);
  gemm_big8<<<1024, 512, 0, stream>>>(u_bf, wbig_bf, bmat, BCN, INNER);
  // 6. cmat = u @ w_c.T
  cast_f32_bf16<<<2048, 256, 0, stream>>>(w_c, wbig_bf, (long)BCN * INNER / 4);
  gemm_big8<<<1024, 512, 0, stream>>>(u_bf, wbig_bf, cmat, BCN, INNER);
  // 7. chunked scan (P/E alias wbig_bf which is dead now)
  scan_pass1<<<(BATCH * NCHUNK * INNER) / 256, 256, 0, stream>>>(
      delta, u_bf, bmat, a_log, Pbuf, Ebuf);
  scan_mid<<<(BATCH * INNER * STATE) / 256, 256, 0, stream>>>(Pbuf, Ebuf);
  scan_pass2<<<(BATCH * NCHUNK * INNER) / 256, 256, 0, stream>>>(
      delta, u_bf, bmat, cmat, gate_bf, a_log, dvec, Ebuf, mixed);
  // 8. out = mixed @ w_out.T   [2048, 1024] f32   nbx=8, nby=16
  cast_f32_bf16<<<2048, 256, 0, stream>>>(w_out, wsmall_bf, (long)MODEL_DIM * INNER / 4);
  gemm_bt<0><<<8 * 16, 256, 0, stream>>>(
      mixed, wsmall_bf, out, nullptr, 8, 16, MODEL_DIM, INNER);
}